// Round 1
// baseline (532.092 us; speedup 1.0000x reference)
//
#include <hip/hip_runtime.h>
#include <hip/hip_bf16.h>
#include <math.h>

#define H_DIM 64
#define G 64
#define ATT 1024
#define EMB 4
#define P 64
#define BB 2048   // batch B = S*P

// ---------------- K1: social pooling -> enc[B][G][H] ----------------
__global__ __launch_bounds__(64) void pool_kernel(const float* __restrict__ h,
                                                  const float* __restrict__ end_pos,
                                                  float* __restrict__ enc) {
    int b = blockIdx.x;          // anchor index (s*P + i)
    int s = b >> 6;              // P == 64
    int i = b & 63;
    int t = threadIdx.x;         // h-dim lane 0..63
    __shared__ float cell[G][H_DIM];
    #pragma unroll
    for (int g = 0; g < G; ++g) cell[g][t] = 0.f;

    float ax = end_pos[2*b], ay = end_pos[2*b+1];
    float tlx = ax - 1.f, tly = ay + 1.f, brx = ax + 1.f, bry = ay - 1.f;
    const float* hseq = h + (size_t)s * P * H_DIM;
    const float* pseq = end_pos + (size_t)s * P * 2;

    for (int j = 0; j < P; ++j) {
        float ox = pseq[2*j], oy = pseq[2*j+1];
        bool oob = (ox >= brx) || (ox <= tlx) || (oy >= tly) || (oy <= bry) || (j == i);
        if (!oob) {
            int cx = (int)floorf((ox - tlx) / 2.0f * 8.0f);
            int cy = (int)floorf((tly - oy) / 2.0f * 8.0f);
            int g = cx + cy * 8;
            cell[g][t] += hseq[j * H_DIM + t];
        }
    }
    float* dst = enc + (size_t)b * G * H_DIM;
    #pragma unroll
    for (int g = 0; g < G; ++g) dst[g * H_DIM + t] = cell[g][t];
}

// ---------------- K2: dec_a = h @ W_dec + b_dec  (block per row) ----------------
__global__ __launch_bounds__(256) void dec_kernel(const float* __restrict__ h,
                                                  const float* __restrict__ W,
                                                  const float* __restrict__ bias,
                                                  float* __restrict__ out) {
    int b = blockIdx.x, t = threadIdx.x;
    __shared__ float hS[H_DIM];
    if (t < H_DIM) hS[t] = h[b * H_DIM + t];
    __syncthreads();
    float a0 = 0, a1 = 0, a2 = 0, a3 = 0;
    #pragma unroll 8
    for (int k = 0; k < H_DIM; ++k) {
        float hk = hS[k];
        const float* w = W + (size_t)k * ATT + t;
        a0 += hk * w[0]; a1 += hk * w[256]; a2 += hk * w[512]; a3 += hk * w[768];
    }
    float* o = out + (size_t)b * ATT + t;
    o[0] = a0 + bias[t]; o[256] = a1 + bias[t+256]; o[512] = a2 + bias[t+512]; o[768] = a3 + bias[t+768];
}

// ---------------- K3: scores[b][g] = relu(enc@W_enc + b_enc + dec_a) . w_full + b_full ----------------
__global__ __launch_bounds__(256) void scores_kernel(const float* __restrict__ enc,
                                                     const float* __restrict__ dec_a,
                                                     const float* __restrict__ W_enc,
                                                     const float* __restrict__ b_enc,
                                                     const float* __restrict__ w_full,
                                                     const float* __restrict__ b_full,
                                                     float* __restrict__ scores) {
    int b = blockIdx.x, t = threadIdx.x;
    __shared__ __align__(16) float encS[64][68];  // [k][g]
    __shared__ __align__(16) float Wt[64][68];    // [k][c]
    __shared__ float red[256][4];

    const float* encB = enc + (size_t)b * G * H_DIM;
    #pragma unroll
    for (int i = 0; i < 16; ++i) {
        int idx = t + 256 * i;
        int g = idx >> 6, k = idx & 63;
        encS[k][g] = encB[idx];
    }
    int m = t & 15, q = t >> 4;
    int g0 = m * 4, c0q = q * 4;
    float sAcc[4] = {0.f, 0.f, 0.f, 0.f};

    for (int nt = 0; nt < 16; ++nt) {
        __syncthreads();
        int n0 = nt * 64;
        #pragma unroll
        for (int i = 0; i < 16; ++i) {
            int idx = t + 256 * i;
            int k = idx >> 6, c = idx & 63;
            Wt[k][c] = W_enc[(size_t)k * ATT + n0 + c];
        }
        __syncthreads();
        float acc[4][4] = {};
        #pragma unroll 8
        for (int k = 0; k < 64; ++k) {
            float4 a4 = *(const float4*)&encS[k][g0];
            float4 w4 = *(const float4*)&Wt[k][c0q];
            acc[0][0] += a4.x * w4.x; acc[0][1] += a4.x * w4.y; acc[0][2] += a4.x * w4.z; acc[0][3] += a4.x * w4.w;
            acc[1][0] += a4.y * w4.x; acc[1][1] += a4.y * w4.y; acc[1][2] += a4.y * w4.z; acc[1][3] += a4.y * w4.w;
            acc[2][0] += a4.z * w4.x; acc[2][1] += a4.z * w4.y; acc[2][2] += a4.z * w4.z; acc[2][3] += a4.z * w4.w;
            acc[3][0] += a4.w * w4.x; acc[3][1] += a4.w * w4.y; acc[3][2] += a4.w * w4.z; acc[3][3] += a4.w * w4.w;
        }
        #pragma unroll
        for (int ci = 0; ci < 4; ++ci) {
            int c = n0 + c0q + ci;
            float d = dec_a[(size_t)b * ATT + c] + b_enc[c];
            float wf = w_full[c];
            #pragma unroll
            for (int gi = 0; gi < 4; ++gi) {
                float v = acc[gi][ci] + d;
                v = v > 0.f ? v : 0.f;
                sAcc[gi] += v * wf;
            }
        }
    }
    red[t][0] = sAcc[0]; red[t][1] = sAcc[1]; red[t][2] = sAcc[2]; red[t][3] = sAcc[3];
    __syncthreads();
    if (t < 64) {
        int g = t, mm = g >> 2, gi = g & 3;
        float ssum = 0.f;
        #pragma unroll
        for (int qq = 0; qq < 16; ++qq) ssum += red[mm + 16 * qq][gi];
        scores[(size_t)b * G + g] = ssum + b_full[0];
    }
}

// ---------------- K4: softmax + ctx + emb -> ctx_emb[B][68] ----------------
__global__ __launch_bounds__(64) void softmax_ctx_kernel(const float* __restrict__ scores,
                                                         const float* __restrict__ enc,
                                                         const float* __restrict__ end_pos,
                                                         const float* __restrict__ rel_pos,
                                                         const float* __restrict__ W_embed,
                                                         const float* __restrict__ b_embed,
                                                         float* __restrict__ ctx_emb) {
    int b = blockIdx.x, t = threadIdx.x;
    float sc = scores[(size_t)b * G + t];
    float mx = sc;
    #pragma unroll
    for (int o = 32; o > 0; o >>= 1) mx = fmaxf(mx, __shfl_xor(mx, o));
    float e = expf(sc - mx);
    float ssum = e;
    #pragma unroll
    for (int o = 32; o > 0; o >>= 1) ssum += __shfl_xor(ssum, o);
    __shared__ float aS[G];
    aS[t] = e / ssum;
    __syncthreads();
    float ctx = 0.f;
    const float* encB = enc + (size_t)b * G * H_DIM;
    #pragma unroll 8
    for (int g = 0; g < G; ++g) ctx += aS[g] * encB[g * H_DIM + t];
    ctx_emb[(size_t)b * 68 + t] = ctx;
    if (t < EMB) {
        float e0 = end_pos[2*b], e1 = end_pos[2*b+1], e2 = rel_pos[2*b], e3 = rel_pos[2*b+1];
        float v = b_embed[t] + e0 * W_embed[0*EMB + t] + e1 * W_embed[1*EMB + t]
                             + e2 * W_embed[2*EMB + t] + e3 * W_embed[3*EMB + t];
        ctx_emb[(size_t)b * 68 + 64 + t] = v > 0.f ? v : 0.f;
    }
}

// ---------------- K5: out = relu(ctx_emb @ W_out + b_out) ----------------
__global__ __launch_bounds__(256) void out_kernel(const float* __restrict__ ctx_emb,
                                                  const float* __restrict__ W_out,
                                                  const float* __restrict__ bias,
                                                  float* __restrict__ out) {
    int b = blockIdx.x, t = threadIdx.x;
    __shared__ float xS[68];
    if (t < 68) xS[t] = ctx_emb[(size_t)b * 68 + t];
    __syncthreads();
    float a0 = 0, a1 = 0, a2 = 0, a3 = 0;
    #pragma unroll 4
    for (int k = 0; k < 68; ++k) {
        float xk = xS[k];
        const float* w = W_out + (size_t)k * ATT + t;
        a0 += xk * w[0]; a1 += xk * w[256]; a2 += xk * w[512]; a3 += xk * w[768];
    }
    float* o = out + (size_t)b * ATT + t;
    float v;
    v = a0 + bias[t];     o[0]   = v > 0.f ? v : 0.f;
    v = a1 + bias[t+256]; o[256] = v > 0.f ? v : 0.f;
    v = a2 + bias[t+512]; o[512] = v > 0.f ? v : 0.f;
    v = a3 + bias[t+768]; o[768] = v > 0.f ? v : 0.f;
}

// ---------------- K6: x = out @ W_mlp + b_mlp  (64x64 tiles) ----------------
__global__ __launch_bounds__(256) void mlp_kernel(const float* __restrict__ A,
                                                  const float* __restrict__ Wm,
                                                  const float* __restrict__ bias,
                                                  float* __restrict__ X) {
    int bm = blockIdx.x, bn = blockIdx.y, t = threadIdx.x;
    __shared__ __align__(16) float At[64][68];  // [k][r]
    __shared__ __align__(16) float Bt[64][68];  // [k][c]
    int r0 = (t & 15) * 4, c0 = (t >> 4) * 4;
    int row0 = bm * 64, col0 = bn * 64;
    float acc[4][4] = {};
    for (int kt = 0; kt < 16; ++kt) {
        int k0 = kt * 64;
        __syncthreads();
        #pragma unroll
        for (int i = 0; i < 16; ++i) {
            int idx = t + 256 * i;
            int hi = idx >> 6, lo = idx & 63;
            At[lo][hi] = A[(size_t)(row0 + hi) * ATT + k0 + lo];
            Bt[hi][lo] = Wm[(size_t)(k0 + hi) * ATT + col0 + lo];
        }
        __syncthreads();
        #pragma unroll 8
        for (int k = 0; k < 64; ++k) {
            float4 a4 = *(const float4*)&At[k][r0];
            float4 b4 = *(const float4*)&Bt[k][c0];
            acc[0][0] += a4.x * b4.x; acc[0][1] += a4.x * b4.y; acc[0][2] += a4.x * b4.z; acc[0][3] += a4.x * b4.w;
            acc[1][0] += a4.y * b4.x; acc[1][1] += a4.y * b4.y; acc[1][2] += a4.y * b4.z; acc[1][3] += a4.y * b4.w;
            acc[2][0] += a4.z * b4.x; acc[2][1] += a4.z * b4.y; acc[2][2] += a4.z * b4.z; acc[2][3] += a4.z * b4.w;
            acc[3][0] += a4.w * b4.x; acc[3][1] += a4.w * b4.y; acc[3][2] += a4.w * b4.z; acc[3][3] += a4.w * b4.w;
        }
    }
    #pragma unroll
    for (int ri = 0; ri < 4; ++ri)
        #pragma unroll
        for (int ci = 0; ci < 4; ++ci) {
            int c = col0 + c0 + ci;
            X[(size_t)(row0 + r0 + ri) * ATT + c] = acc[ri][ci] + bias[c];
        }
}

// ---------------- K7a: BN stats (sum, sumsq per feature) ----------------
__global__ __launch_bounds__(256) void bnstat_kernel(const float* __restrict__ X,
                                                     float* __restrict__ sums) {
    int f = (blockIdx.x & 3) * 256 + threadIdx.x;
    int rbeg = (blockIdx.x >> 2) * 128;
    float s = 0.f, s2 = 0.f;
    for (int r = 0; r < 128; ++r) {
        float v = X[(size_t)(rbeg + r) * ATT + f];
        s += v; s2 += v * v;
    }
    atomicAdd(&sums[f], s);
    atomicAdd(&sums[ATT + f], s2);
}

// ---------------- K7b: normalize + relu -> d_out ----------------
__global__ __launch_bounds__(256) void bn_kernel(const float* __restrict__ X,
                                                 const float* __restrict__ sums,
                                                 const float* __restrict__ gamma,
                                                 const float* __restrict__ beta,
                                                 float* __restrict__ out) {
    size_t i = (size_t)blockIdx.x * 256 + threadIdx.x;
    int f = (int)(i & 1023);
    float mu = sums[f] * (1.f / BB);
    float var = sums[ATT + f] * (1.f / BB) - mu * mu;
    float v = (X[i] - mu) * rsqrtf(var + 1e-5f) * gamma[f] + beta[f];
    out[i] = v > 0.f ? v : 0.f;
}

extern "C" void kernel_launch(void* const* d_in, const int* in_sizes, int n_in,
                              void* d_out, int out_size, void* d_ws, size_t ws_size,
                              hipStream_t stream) {
    const float* h        = (const float*)d_in[0];
    const float* end_pos  = (const float*)d_in[2];
    const float* rel_pos  = (const float*)d_in[3];
    const float* W_enc    = (const float*)d_in[4];
    const float* b_enc    = (const float*)d_in[5];
    const float* W_dec    = (const float*)d_in[6];
    const float* b_dec    = (const float*)d_in[7];
    const float* w_full   = (const float*)d_in[8];
    const float* b_full   = (const float*)d_in[9];
    const float* W_embed  = (const float*)d_in[10];
    const float* b_embed  = (const float*)d_in[11];
    const float* W_out    = (const float*)d_in[12];
    const float* b_out    = (const float*)d_in[13];
    const float* W_mlp    = (const float*)d_in[14];
    const float* b_mlp    = (const float*)d_in[15];
    const float* bn_gamma = (const float*)d_in[16];
    const float* bn_beta  = (const float*)d_in[17];

    float* ws      = (float*)d_ws;
    float* enc     = ws;                        // 8,388,608 floats (33.55 MB)
    float* dec_a   = ws + 8388608;              // 2,097,152
    float* scores  = ws + 10485760;             // 131,072
    float* ctx_emb = ws + 10616832;             // 139,264
    float* sums    = ws + 10756096;             // 2,048
    float* outb    = dec_a;                     // alias: dec_a dead after K3
    float* x       = enc;                       // alias: enc dead after K4

    hipMemsetAsync(sums, 0, 2048 * sizeof(float), stream);

    pool_kernel<<<BB, 64, 0, stream>>>(h, end_pos, enc);
    dec_kernel<<<BB, 256, 0, stream>>>(h, W_dec, b_dec, dec_a);
    scores_kernel<<<BB, 256, 0, stream>>>(enc, dec_a, W_enc, b_enc, w_full, b_full, scores);
    softmax_ctx_kernel<<<BB, 64, 0, stream>>>(scores, enc, end_pos, rel_pos, W_embed, b_embed, ctx_emb);
    out_kernel<<<BB, 256, 0, stream>>>(ctx_emb, W_out, b_out, outb);
    mlp_kernel<<<dim3(32, 16), 256, 0, stream>>>(outb, W_mlp, b_mlp, x);
    bnstat_kernel<<<64, 256, 0, stream>>>(x, sums);
    bn_kernel<<<8192, 256, 0, stream>>>(x, sums, bn_gamma, bn_beta, (float*)d_out);
}

// Round 2
// 429.813 us; speedup vs baseline: 1.2380x; 1.2380x over previous
//
#include <hip/hip_runtime.h>
#include <hip/hip_bf16.h>
#include <math.h>

#define H_DIM 64
#define G 64
#define ATT 1024
#define EMB 4
#define P 64
#define BB 2048   // batch B = S*P
#define MAXROWS 129088  // 2048*63 rounded up to multiple of 64

// ---------------- K1: social pooling -> nonzero rows of enc + compact row list ----------------
__global__ __launch_bounds__(64) void pool_kernel(const float* __restrict__ h,
                                                  const float* __restrict__ end_pos,
                                                  float* __restrict__ enc,
                                                  int* __restrict__ rowidx,
                                                  int* __restrict__ cntA,
                                                  int* __restrict__ baseA,
                                                  int* __restrict__ counter) {
    int b = blockIdx.x;          // anchor index (s*P + i)
    int s = b >> 6;              // P == 64
    int i = b & 63;
    int t = threadIdx.x;         // h-dim lane 0..63
    __shared__ float cell[G][H_DIM];
    #pragma unroll
    for (int g = 0; g < G; ++g) cell[g][t] = 0.f;

    float ax = end_pos[2*b], ay = end_pos[2*b+1];
    float tlx = ax - 1.f, tly = ay + 1.f, brx = ax + 1.f, bry = ay - 1.f;
    const float* hseq = h + (size_t)s * P * H_DIM;
    const float* pseq = end_pos + (size_t)s * P * 2;

    unsigned long long hits = 0ull;   // wave-uniform
    for (int j = 0; j < P; ++j) {
        float ox = pseq[2*j], oy = pseq[2*j+1];
        bool oob = (ox >= brx) || (ox <= tlx) || (oy >= tly) || (oy <= bry) || (j == i);
        if (!oob) {
            int cx = (int)floorf((ox - tlx) / 2.0f * 8.0f);
            int cy = (int)floorf((tly - oy) / 2.0f * 8.0f);
            int g = cx + cy * 8;
            hits |= (1ull << g);
            cell[g][t] += hseq[j * H_DIM + t];
        }
    }
    int n_nz = __popcll(hits);
    int base = 0;
    if (t == 0) base = atomicAdd(counter, n_nz);
    base = __shfl(base, 0);
    if (t == 0) { cntA[b] = n_nz; baseA[b] = base; }

    #pragma unroll 1
    for (int g = 0; g < G; ++g) {
        if ((hits >> g) & 1ull) {  // wave-uniform branch
            int slot = __popcll(hits & ((1ull << g) - 1ull));
            int row = base + slot;
            enc[((size_t)(b * G + g)) * H_DIM + t] = cell[g][t];
            if (t == 0) rowidx[row] = b * G + g;
        }
    }
}

// ---------------- K2: dec_r = h @ W_dec + b_dec + b_enc ; s_empty = relu(dec_r).w_full + b_full ----------------
__global__ __launch_bounds__(256) void dec_kernel(const float* __restrict__ h,
                                                  const float* __restrict__ W,
                                                  const float* __restrict__ b_dec,
                                                  const float* __restrict__ b_enc,
                                                  const float* __restrict__ w_full,
                                                  const float* __restrict__ b_full,
                                                  float* __restrict__ dec_r,
                                                  float* __restrict__ s_empty) {
    int b = blockIdx.x, t = threadIdx.x;
    __shared__ float hS[H_DIM];
    __shared__ float red[256];
    if (t < H_DIM) hS[t] = h[b * H_DIM + t];
    __syncthreads();
    float a0 = 0, a1 = 0, a2 = 0, a3 = 0;
    #pragma unroll 8
    for (int k = 0; k < H_DIM; ++k) {
        float hk = hS[k];
        const float* w = W + (size_t)k * ATT + t;
        a0 += hk * w[0]; a1 += hk * w[256]; a2 += hk * w[512]; a3 += hk * w[768];
    }
    float* o = dec_r + (size_t)b * ATT + t;
    float v0 = a0 + b_dec[t]     + b_enc[t];
    float v1 = a1 + b_dec[t+256] + b_enc[t+256];
    float v2 = a2 + b_dec[t+512] + b_enc[t+512];
    float v3 = a3 + b_dec[t+768] + b_enc[t+768];
    o[0] = v0; o[256] = v1; o[512] = v2; o[768] = v3;
    float sm = fmaxf(v0, 0.f) * w_full[t]     + fmaxf(v1, 0.f) * w_full[t+256]
             + fmaxf(v2, 0.f) * w_full[t+512] + fmaxf(v3, 0.f) * w_full[t+768];
    red[t] = sm;
    __syncthreads();
    for (int off = 128; off > 0; off >>= 1) {
        if (t < off) red[t] += red[t + off];
        __syncthreads();
    }
    if (t == 0) s_empty[b] = red[0] + b_full[0];
}

// ---------------- K3: scores over compact rows: score_c[r] = relu(enc_r@W_enc + dec_r[b]) . w_full + b_full ----------------
__global__ __launch_bounds__(256) void scoresC_kernel(const float* __restrict__ enc,
                                                      const int* __restrict__ rowidx,
                                                      const int* __restrict__ counter,
                                                      const float* __restrict__ dec_r,
                                                      const float* __restrict__ W_enc,
                                                      const float* __restrict__ w_full,
                                                      const float* __restrict__ b_full,
                                                      float* __restrict__ score_c) {
    int M = counter[0];
    int row0 = blockIdx.x * 64;
    if (row0 >= M) return;
    int t = threadIdx.x;
    __shared__ __align__(16) float encS[64][68];  // [k][r]
    __shared__ __align__(16) float Wt[64][68];    // [k][c]
    __shared__ float red[256][4];
    __shared__ int rowS[64];

    if (t < 64) rowS[t] = (row0 + t < M) ? rowidx[row0 + t] : 0;
    __syncthreads();
    #pragma unroll
    for (int i = 0; i < 16; ++i) {
        int idx = t + 256 * i;
        int r = idx >> 6, k = idx & 63;
        encS[k][r] = enc[(size_t)rowS[r] * H_DIM + k];
    }
    int m = t & 15, q = t >> 4;
    int g0 = m * 4, c0q = q * 4;
    float sAcc[4] = {0.f, 0.f, 0.f, 0.f};

    for (int nt = 0; nt < 16; ++nt) {
        __syncthreads();
        int n0 = nt * 64;
        #pragma unroll
        for (int i = 0; i < 16; ++i) {
            int idx = t + 256 * i;
            int k = idx >> 6, c = idx & 63;
            Wt[k][c] = W_enc[(size_t)k * ATT + n0 + c];
        }
        __syncthreads();
        float acc[4][4] = {};
        #pragma unroll 8
        for (int k = 0; k < 64; ++k) {
            float4 a4 = *(const float4*)&encS[k][g0];
            float4 w4 = *(const float4*)&Wt[k][c0q];
            acc[0][0] += a4.x * w4.x; acc[0][1] += a4.x * w4.y; acc[0][2] += a4.x * w4.z; acc[0][3] += a4.x * w4.w;
            acc[1][0] += a4.y * w4.x; acc[1][1] += a4.y * w4.y; acc[1][2] += a4.y * w4.z; acc[1][3] += a4.y * w4.w;
            acc[2][0] += a4.z * w4.x; acc[2][1] += a4.z * w4.y; acc[2][2] += a4.z * w4.z; acc[2][3] += a4.z * w4.w;
            acc[3][0] += a4.w * w4.x; acc[3][1] += a4.w * w4.y; acc[3][2] += a4.w * w4.z; acc[3][3] += a4.w * w4.w;
        }
        float4 wf4 = *(const float4*)&w_full[n0 + c0q];
        #pragma unroll
        for (int gi = 0; gi < 4; ++gi) {
            int bb = rowS[g0 + gi] >> 6;
            float4 d4 = *(const float4*)&dec_r[(size_t)bb * ATT + n0 + c0q];
            float v;
            v = acc[gi][0] + d4.x; sAcc[gi] += fmaxf(v, 0.f) * wf4.x;
            v = acc[gi][1] + d4.y; sAcc[gi] += fmaxf(v, 0.f) * wf4.y;
            v = acc[gi][2] + d4.z; sAcc[gi] += fmaxf(v, 0.f) * wf4.z;
            v = acc[gi][3] + d4.w; sAcc[gi] += fmaxf(v, 0.f) * wf4.w;
        }
    }
    red[t][0] = sAcc[0]; red[t][1] = sAcc[1]; red[t][2] = sAcc[2]; red[t][3] = sAcc[3];
    __syncthreads();
    if (t < 64) {
        int row = row0 + t;
        if (row < M) {
            int mm = t >> 2, gi = t & 3;
            float ssum = 0.f;
            #pragma unroll
            for (int qq = 0; qq < 16; ++qq) ssum += red[mm + 16 * qq][gi];
            score_c[row] = ssum + b_full[0];
        }
    }
}

// ---------------- K4: softmax over {nz scores, (64-cnt) copies of s_empty} + ctx + emb ----------------
__global__ __launch_bounds__(64) void softmax_ctx_kernel(const float* __restrict__ score_c,
                                                         const int* __restrict__ rowidx,
                                                         const int* __restrict__ cntA,
                                                         const int* __restrict__ baseA,
                                                         const float* __restrict__ s_empty,
                                                         const float* __restrict__ enc,
                                                         const float* __restrict__ end_pos,
                                                         const float* __restrict__ rel_pos,
                                                         const float* __restrict__ W_embed,
                                                         const float* __restrict__ b_embed,
                                                         float* __restrict__ ctx_emb) {
    int b = blockIdx.x, t = threadIdx.x;
    int cnt = cntA[b], base = baseA[b];
    float se = s_empty[b];
    float sc = se;
    int ri = 0;
    if (t < cnt) { sc = score_c[base + t]; ri = rowidx[base + t]; }
    float mx = sc;
    #pragma unroll
    for (int o = 32; o > 0; o >>= 1) mx = fmaxf(mx, __shfl_xor(mx, o));
    float e = expf(sc - mx);
    float ssum = e;
    #pragma unroll
    for (int o = 32; o > 0; o >>= 1) ssum += __shfl_xor(ssum, o);
    __shared__ float aS[G];
    __shared__ int rS[G];
    aS[t] = e / ssum;
    rS[t] = ri;
    __syncthreads();
    float ctx = 0.f;
    for (int i = 0; i < cnt; ++i)
        ctx += aS[i] * enc[(size_t)rS[i] * H_DIM + t];
    ctx_emb[(size_t)b * 68 + t] = ctx;
    if (t < EMB) {
        float e0 = end_pos[2*b], e1 = end_pos[2*b+1], e2 = rel_pos[2*b], e3 = rel_pos[2*b+1];
        float v = b_embed[t] + e0 * W_embed[0*EMB + t] + e1 * W_embed[1*EMB + t]
                             + e2 * W_embed[2*EMB + t] + e3 * W_embed[3*EMB + t];
        ctx_emb[(size_t)b * 68 + 64 + t] = v > 0.f ? v : 0.f;
    }
}

// ---------------- K5: out = relu(ctx_emb @ W_out + b_out) ----------------
__global__ __launch_bounds__(256) void out_kernel(const float* __restrict__ ctx_emb,
                                                  const float* __restrict__ W_out,
                                                  const float* __restrict__ bias,
                                                  float* __restrict__ out) {
    int b = blockIdx.x, t = threadIdx.x;
    __shared__ float xS[68];
    if (t < 68) xS[t] = ctx_emb[(size_t)b * 68 + t];
    __syncthreads();
    float a0 = 0, a1 = 0, a2 = 0, a3 = 0;
    #pragma unroll 4
    for (int k = 0; k < 68; ++k) {
        float xk = xS[k];
        const float* w = W_out + (size_t)k * ATT + t;
        a0 += xk * w[0]; a1 += xk * w[256]; a2 += xk * w[512]; a3 += xk * w[768];
    }
    float* o = out + (size_t)b * ATT + t;
    float v;
    v = a0 + bias[t];     o[0]   = v > 0.f ? v : 0.f;
    v = a1 + bias[t+256]; o[256] = v > 0.f ? v : 0.f;
    v = a2 + bias[t+512]; o[512] = v > 0.f ? v : 0.f;
    v = a3 + bias[t+768]; o[768] = v > 0.f ? v : 0.f;
}

// ---------------- K6: x = out @ W_mlp + b_mlp  (64x64 tiles) ----------------
__global__ __launch_bounds__(256) void mlp_kernel(const float* __restrict__ A,
                                                  const float* __restrict__ Wm,
                                                  const float* __restrict__ bias,
                                                  float* __restrict__ X) {
    int bm = blockIdx.x, bn = blockIdx.y, t = threadIdx.x;
    __shared__ __align__(16) float At[64][68];  // [k][r]
    __shared__ __align__(16) float Bt[64][68];  // [k][c]
    int r0 = (t & 15) * 4, c0 = (t >> 4) * 4;
    int row0 = bm * 64, col0 = bn * 64;
    float acc[4][4] = {};
    for (int kt = 0; kt < 16; ++kt) {
        int k0 = kt * 64;
        __syncthreads();
        #pragma unroll
        for (int i = 0; i < 16; ++i) {
            int idx = t + 256 * i;
            int hi = idx >> 6, lo = idx & 63;
            At[lo][hi] = A[(size_t)(row0 + hi) * ATT + k0 + lo];
            Bt[hi][lo] = Wm[(size_t)(k0 + hi) * ATT + col0 + lo];
        }
        __syncthreads();
        #pragma unroll 8
        for (int k = 0; k < 64; ++k) {
            float4 a4 = *(const float4*)&At[k][r0];
            float4 b4 = *(const float4*)&Bt[k][c0];
            acc[0][0] += a4.x * b4.x; acc[0][1] += a4.x * b4.y; acc[0][2] += a4.x * b4.z; acc[0][3] += a4.x * b4.w;
            acc[1][0] += a4.y * b4.x; acc[1][1] += a4.y * b4.y; acc[1][2] += a4.y * b4.z; acc[1][3] += a4.y * b4.w;
            acc[2][0] += a4.z * b4.x; acc[2][1] += a4.z * b4.y; acc[2][2] += a4.z * b4.z; acc[2][3] += a4.z * b4.w;
            acc[3][0] += a4.w * b4.x; acc[3][1] += a4.w * b4.y; acc[3][2] += a4.w * b4.z; acc[3][3] += a4.w * b4.w;
        }
    }
    #pragma unroll
    for (int ri = 0; ri < 4; ++ri)
        #pragma unroll
        for (int ci = 0; ci < 4; ++ci) {
            int c = col0 + c0 + ci;
            X[(size_t)(row0 + r0 + ri) * ATT + c] = acc[ri][ci] + bias[c];
        }
}

// ---------------- K7a: BN stats (sum, sumsq per feature) ----------------
__global__ __launch_bounds__(256) void bnstat_kernel(const float* __restrict__ X,
                                                     float* __restrict__ sums) {
    int f = (blockIdx.x & 3) * 256 + threadIdx.x;
    int rbeg = (blockIdx.x >> 2) * 128;
    float s = 0.f, s2 = 0.f;
    for (int r = 0; r < 128; ++r) {
        float v = X[(size_t)(rbeg + r) * ATT + f];
        s += v; s2 += v * v;
    }
    atomicAdd(&sums[f], s);
    atomicAdd(&sums[ATT + f], s2);
}

// ---------------- K7b: normalize + relu -> d_out ----------------
__global__ __launch_bounds__(256) void bn_kernel(const float* __restrict__ X,
                                                 const float* __restrict__ sums,
                                                 const float* __restrict__ gamma,
                                                 const float* __restrict__ beta,
                                                 float* __restrict__ out) {
    size_t i = (size_t)blockIdx.x * 256 + threadIdx.x;
    int f = (int)(i & 1023);
    float mu = sums[f] * (1.f / BB);
    float var = sums[ATT + f] * (1.f / BB) - mu * mu;
    float v = (X[i] - mu) * rsqrtf(var + 1e-5f) * gamma[f] + beta[f];
    out[i] = v > 0.f ? v : 0.f;
}

extern "C" void kernel_launch(void* const* d_in, const int* in_sizes, int n_in,
                              void* d_out, int out_size, void* d_ws, size_t ws_size,
                              hipStream_t stream) {
    const float* h        = (const float*)d_in[0];
    const float* end_pos  = (const float*)d_in[2];
    const float* rel_pos  = (const float*)d_in[3];
    const float* W_enc    = (const float*)d_in[4];
    const float* b_enc    = (const float*)d_in[5];
    const float* W_dec    = (const float*)d_in[6];
    const float* b_dec    = (const float*)d_in[7];
    const float* w_full   = (const float*)d_in[8];
    const float* b_full   = (const float*)d_in[9];
    const float* W_embed  = (const float*)d_in[10];
    const float* b_embed  = (const float*)d_in[11];
    const float* W_out    = (const float*)d_in[12];
    const float* b_out    = (const float*)d_in[13];
    const float* W_mlp    = (const float*)d_in[14];
    const float* b_mlp    = (const float*)d_in[15];
    const float* bn_gamma = (const float*)d_in[16];
    const float* bn_beta  = (const float*)d_in[17];

    float* ws      = (float*)d_ws;
    // Live layout (floats):
    float* enc     = ws;                         // [0 , 8,388,608) dense enc, only nonzero rows written
    float* dec_r   = ws + 8388608;               // [8,388,608 , 10,485,760)
    int*   rowidx  = (int*)(ws + 10485760);      // [10,485,760 , 10,614,848)
    float* score_c = ws + 10614848;              // [10,614,848 , 10,743,936)
    float* s_empty = ws + 10743936;              // 2048
    int*   cntA    = (int*)(ws + 10745984);      // 2048
    int*   baseA   = (int*)(ws + 10748032);      // 2048
    int*   counter = (int*)(ws + 10750080);      // 64 (1 used)
    // Aliases (regions dead by the time these are written):
    float* outb    = ws;                         // alias enc[0 , 2,097,152)   (enc dead after K4)
    float* x       = ws + 2097152;               // alias enc[2,097,152 , 4,194,304)
    float* ctx_emb = ws + 8388608;               // alias dec_r (dead after K3), 139,264
    float* sums    = ws + 8527872;               // alias dec_r + 139,264, 2048

    hipMemsetAsync(counter, 0, 64 * sizeof(int), stream);

    pool_kernel<<<BB, 64, 0, stream>>>(h, end_pos, enc, rowidx, cntA, baseA, counter);
    dec_kernel<<<BB, 256, 0, stream>>>(h, W_dec, b_dec, b_enc, w_full, b_full, dec_r, s_empty);
    scoresC_kernel<<<MAXROWS / 64, 256, 0, stream>>>(enc, rowidx, counter, dec_r, W_enc, w_full, b_full, score_c);
    softmax_ctx_kernel<<<BB, 64, 0, stream>>>(score_c, rowidx, cntA, baseA, s_empty, enc,
                                              end_pos, rel_pos, W_embed, b_embed, ctx_emb);
    out_kernel<<<BB, 256, 0, stream>>>(ctx_emb, W_out, b_out, outb);
    mlp_kernel<<<dim3(32, 16), 256, 0, stream>>>(outb, W_mlp, b_mlp, x);
    hipMemsetAsync(sums, 0, 2048 * sizeof(float), stream);
    bnstat_kernel<<<64, 256, 0, stream>>>(x, sums);
    bn_kernel<<<8192, 256, 0, stream>>>(x, sums, bn_gamma, bn_beta, (float*)d_out);
}

// Round 3
// 284.147 us; speedup vs baseline: 1.8726x; 1.5126x over previous
//
#include <hip/hip_runtime.h>
#include <hip/hip_bf16.h>
#include <math.h>

#define H_DIM 64
#define G 64
#define ATT 1024
#define EMB 4
#define P 64
#define BB 2048   // batch B = S*P
#define MAXROWS 129088  // 2048*63 rounded up to multiple of 64

typedef __attribute__((ext_vector_type(8))) short short8;
typedef __attribute__((ext_vector_type(4))) float floatx4;

__device__ inline ushort f2bf(float v) {
    __hip_bfloat16 b = __float2bfloat16(v);
    return *(ushort*)&b;
}

// ---------------- K1: social pooling -> nonzero rows of enc + compact row list ----------------
__global__ __launch_bounds__(64) void pool_kernel(const float* __restrict__ h,
                                                  const float* __restrict__ end_pos,
                                                  float* __restrict__ enc,
                                                  int* __restrict__ rowidx,
                                                  int* __restrict__ cntA,
                                                  int* __restrict__ baseA,
                                                  int* __restrict__ counter) {
    int b = blockIdx.x;          // anchor index (s*P + i)
    int s = b >> 6;              // P == 64
    int i = b & 63;
    int t = threadIdx.x;         // h-dim lane 0..63
    __shared__ float cell[G][H_DIM];
    #pragma unroll
    for (int g = 0; g < G; ++g) cell[g][t] = 0.f;

    float ax = end_pos[2*b], ay = end_pos[2*b+1];
    float tlx = ax - 1.f, tly = ay + 1.f, brx = ax + 1.f, bry = ay - 1.f;
    const float* hseq = h + (size_t)s * P * H_DIM;
    const float* pseq = end_pos + (size_t)s * P * 2;

    unsigned long long hits = 0ull;   // wave-uniform
    for (int j = 0; j < P; ++j) {
        float ox = pseq[2*j], oy = pseq[2*j+1];
        bool oob = (ox >= brx) || (ox <= tlx) || (oy >= tly) || (oy <= bry) || (j == i);
        if (!oob) {
            int cx = (int)floorf((ox - tlx) / 2.0f * 8.0f);
            int cy = (int)floorf((tly - oy) / 2.0f * 8.0f);
            int g = cx + cy * 8;
            hits |= (1ull << g);
            cell[g][t] += hseq[j * H_DIM + t];
        }
    }
    int n_nz = __popcll(hits);
    int base = 0;
    if (t == 0) base = atomicAdd(counter, n_nz);
    base = __shfl(base, 0);
    if (t == 0) { cntA[b] = n_nz; baseA[b] = base; }

    #pragma unroll 1
    for (int g = 0; g < G; ++g) {
        if ((hits >> g) & 1ull) {  // wave-uniform branch
            int slot = __popcll(hits & ((1ull << g) - 1ull));
            int row = base + slot;
            enc[((size_t)(b * G + g)) * H_DIM + t] = cell[g][t];
            if (t == 0) rowidx[row] = b * G + g;
        }
    }
}

// ---------------- K2: dec_r = h @ W_dec + b_dec + b_enc ; s_empty = relu(dec_r).w_full + b_full ----------------
__global__ __launch_bounds__(256) void dec_kernel(const float* __restrict__ h,
                                                  const float* __restrict__ W,
                                                  const float* __restrict__ b_dec,
                                                  const float* __restrict__ b_enc,
                                                  const float* __restrict__ w_full,
                                                  const float* __restrict__ b_full,
                                                  float* __restrict__ dec_r,
                                                  float* __restrict__ s_empty) {
    int b = blockIdx.x, t = threadIdx.x;
    __shared__ float hS[H_DIM];
    __shared__ float red[256];
    if (t < H_DIM) hS[t] = h[b * H_DIM + t];
    __syncthreads();
    float a0 = 0, a1 = 0, a2 = 0, a3 = 0;
    #pragma unroll 8
    for (int k = 0; k < H_DIM; ++k) {
        float hk = hS[k];
        const float* w = W + (size_t)k * ATT + t;
        a0 += hk * w[0]; a1 += hk * w[256]; a2 += hk * w[512]; a3 += hk * w[768];
    }
    float* o = dec_r + (size_t)b * ATT + t;
    float v0 = a0 + b_dec[t]     + b_enc[t];
    float v1 = a1 + b_dec[t+256] + b_enc[t+256];
    float v2 = a2 + b_dec[t+512] + b_enc[t+512];
    float v3 = a3 + b_dec[t+768] + b_enc[t+768];
    o[0] = v0; o[256] = v1; o[512] = v2; o[768] = v3;
    float sm = fmaxf(v0, 0.f) * w_full[t]     + fmaxf(v1, 0.f) * w_full[t+256]
             + fmaxf(v2, 0.f) * w_full[t+512] + fmaxf(v3, 0.f) * w_full[t+768];
    red[t] = sm;
    __syncthreads();
    for (int off = 128; off > 0; off >>= 1) {
        if (t < off) red[t] += red[t + off];
        __syncthreads();
    }
    if (t == 0) s_empty[b] = red[0] + b_full[0];
}

// ---------------- K3: scores over compact rows ----------------
__global__ __launch_bounds__(256) void scoresC_kernel(const float* __restrict__ enc,
                                                      const int* __restrict__ rowidx,
                                                      const int* __restrict__ counter,
                                                      const float* __restrict__ dec_r,
                                                      const float* __restrict__ W_enc,
                                                      const float* __restrict__ w_full,
                                                      const float* __restrict__ b_full,
                                                      float* __restrict__ score_c) {
    int M = counter[0];
    int row0 = blockIdx.x * 64;
    if (row0 >= M) return;
    int t = threadIdx.x;
    __shared__ __align__(16) float encS[64][68];  // [k][r]
    __shared__ __align__(16) float Wt[64][68];    // [k][c]
    __shared__ float red[256][4];
    __shared__ int rowS[64];

    if (t < 64) rowS[t] = (row0 + t < M) ? rowidx[row0 + t] : 0;
    __syncthreads();
    #pragma unroll
    for (int i = 0; i < 16; ++i) {
        int idx = t + 256 * i;
        int r = idx >> 6, k = idx & 63;
        encS[k][r] = enc[(size_t)rowS[r] * H_DIM + k];
    }
    int m = t & 15, q = t >> 4;
    int g0 = m * 4, c0q = q * 4;
    float sAcc[4] = {0.f, 0.f, 0.f, 0.f};

    for (int nt = 0; nt < 16; ++nt) {
        __syncthreads();
        int n0 = nt * 64;
        #pragma unroll
        for (int i = 0; i < 16; ++i) {
            int idx = t + 256 * i;
            int k = idx >> 6, c = idx & 63;
            Wt[k][c] = W_enc[(size_t)k * ATT + n0 + c];
        }
        __syncthreads();
        float acc[4][4] = {};
        #pragma unroll 8
        for (int k = 0; k < 64; ++k) {
            float4 a4 = *(const float4*)&encS[k][g0];
            float4 w4 = *(const float4*)&Wt[k][c0q];
            acc[0][0] += a4.x * w4.x; acc[0][1] += a4.x * w4.y; acc[0][2] += a4.x * w4.z; acc[0][3] += a4.x * w4.w;
            acc[1][0] += a4.y * w4.x; acc[1][1] += a4.y * w4.y; acc[1][2] += a4.y * w4.z; acc[1][3] += a4.y * w4.w;
            acc[2][0] += a4.z * w4.x; acc[2][1] += a4.z * w4.y; acc[2][2] += a4.z * w4.z; acc[2][3] += a4.z * w4.w;
            acc[3][0] += a4.w * w4.x; acc[3][1] += a4.w * w4.y; acc[3][2] += a4.w * w4.z; acc[3][3] += a4.w * w4.w;
        }
        float4 wf4 = *(const float4*)&w_full[n0 + c0q];
        #pragma unroll
        for (int gi = 0; gi < 4; ++gi) {
            int bb = rowS[g0 + gi] >> 6;
            float4 d4 = *(const float4*)&dec_r[(size_t)bb * ATT + n0 + c0q];
            float v;
            v = acc[gi][0] + d4.x; sAcc[gi] += fmaxf(v, 0.f) * wf4.x;
            v = acc[gi][1] + d4.y; sAcc[gi] += fmaxf(v, 0.f) * wf4.y;
            v = acc[gi][2] + d4.z; sAcc[gi] += fmaxf(v, 0.f) * wf4.z;
            v = acc[gi][3] + d4.w; sAcc[gi] += fmaxf(v, 0.f) * wf4.w;
        }
    }
    red[t][0] = sAcc[0]; red[t][1] = sAcc[1]; red[t][2] = sAcc[2]; red[t][3] = sAcc[3];
    __syncthreads();
    if (t < 64) {
        int row = row0 + t;
        if (row < M) {
            int mm = t >> 2, gi = t & 3;
            float ssum = 0.f;
            #pragma unroll
            for (int qq = 0; qq < 16; ++qq) ssum += red[mm + 16 * qq][gi];
            score_c[row] = ssum + b_full[0];
        }
    }
}

// ---------------- K4: softmax + ctx + emb ----------------
__global__ __launch_bounds__(64) void softmax_ctx_kernel(const float* __restrict__ score_c,
                                                         const int* __restrict__ rowidx,
                                                         const int* __restrict__ cntA,
                                                         const int* __restrict__ baseA,
                                                         const float* __restrict__ s_empty,
                                                         const float* __restrict__ enc,
                                                         const float* __restrict__ end_pos,
                                                         const float* __restrict__ rel_pos,
                                                         const float* __restrict__ W_embed,
                                                         const float* __restrict__ b_embed,
                                                         float* __restrict__ ctx_emb) {
    int b = blockIdx.x, t = threadIdx.x;
    int cnt = cntA[b], base = baseA[b];
    float se = s_empty[b];
    float sc = se;
    int ri = 0;
    if (t < cnt) { sc = score_c[base + t]; ri = rowidx[base + t]; }
    float mx = sc;
    #pragma unroll
    for (int o = 32; o > 0; o >>= 1) mx = fmaxf(mx, __shfl_xor(mx, o));
    float e = expf(sc - mx);
    float ssum = e;
    #pragma unroll
    for (int o = 32; o > 0; o >>= 1) ssum += __shfl_xor(ssum, o);
    __shared__ float aS[G];
    __shared__ int rS[G];
    aS[t] = e / ssum;
    rS[t] = ri;
    __syncthreads();
    float ctx = 0.f;
    for (int i = 0; i < cnt; ++i)
        ctx += aS[i] * enc[(size_t)rS[i] * H_DIM + t];
    ctx_emb[(size_t)b * 68 + t] = ctx;
    if (t < EMB) {
        float e0 = end_pos[2*b], e1 = end_pos[2*b+1], e2 = rel_pos[2*b], e3 = rel_pos[2*b+1];
        float v = b_embed[t] + e0 * W_embed[0*EMB + t] + e1 * W_embed[1*EMB + t]
                             + e2 * W_embed[2*EMB + t] + e3 * W_embed[3*EMB + t];
        ctx_emb[(size_t)b * 68 + 64 + t] = v > 0.f ? v : 0.f;
    }
}

// ---------------- K5: out_bf16 = bf16(relu(ctx_emb @ W_out + b_out)) ----------------
__global__ __launch_bounds__(256) void out_kernel(const float* __restrict__ ctx_emb,
                                                  const float* __restrict__ W_out,
                                                  const float* __restrict__ bias,
                                                  ushort* __restrict__ out) {
    int b = blockIdx.x, t = threadIdx.x;
    __shared__ float xS[68];
    if (t < 68) xS[t] = ctx_emb[(size_t)b * 68 + t];
    __syncthreads();
    float a0 = 0, a1 = 0, a2 = 0, a3 = 0;
    #pragma unroll 4
    for (int k = 0; k < 68; ++k) {
        float xk = xS[k];
        const float* w = W_out + (size_t)k * ATT + t;
        a0 += xk * w[0]; a1 += xk * w[256]; a2 += xk * w[512]; a3 += xk * w[768];
    }
    ushort* o = out + (size_t)b * ATT + t;
    o[0]   = f2bf(fmaxf(a0 + bias[t],     0.f));
    o[256] = f2bf(fmaxf(a1 + bias[t+256], 0.f));
    o[512] = f2bf(fmaxf(a2 + bias[t+512], 0.f));
    o[768] = f2bf(fmaxf(a3 + bias[t+768], 0.f));
}

// ---------------- K5b: Wt[n][k] = bf16(W_mlp[k][n]) ----------------
__global__ __launch_bounds__(256) void wt_kernel(const float* __restrict__ Wm,
                                                 ushort* __restrict__ Wt) {
    __shared__ float tile[64][65];
    int k0 = blockIdx.x * 64, n0 = blockIdx.y * 64;
    int t = threadIdx.x;
    #pragma unroll
    for (int i = 0; i < 16; ++i) {
        int flat = t + 256 * i;
        int r = flat >> 6, c = flat & 63;
        tile[r][c] = Wm[(size_t)(k0 + r) * ATT + n0 + c];
    }
    __syncthreads();
    #pragma unroll
    for (int i = 0; i < 16; ++i) {
        int flat = t + 256 * i;
        int r = flat >> 6, c = flat & 63;
        Wt[(size_t)(n0 + r) * ATT + k0 + c] = f2bf(tile[c][r]);
    }
}

// ---------------- K6: x = out_bf16 @ Wt^T + b_mlp  (MFMA, 64x128 block tile) ----------------
__global__ __launch_bounds__(256) void mlp_mfma_kernel(const ushort* __restrict__ A,   // [2048][1024] bf16
                                                       const ushort* __restrict__ Bt,  // [1024 n][1024 k] bf16
                                                       const float* __restrict__ bias,
                                                       float* __restrict__ X) {
    int t = threadIdx.x;
    int w = t >> 6, lane = t & 63;
    int m0 = blockIdx.x * 64, n1 = blockIdx.y * 128;
    // rows padded to 72 bf16 (144 B): row stride = 36 words -> 2-way bank aliasing (free)
    __shared__ __align__(16) ushort Asm[64][72];
    __shared__ __align__(16) ushort Bsm[128][72];

    floatx4 acc[4][2];
    #pragma unroll
    for (int i = 0; i < 4; ++i)
        #pragma unroll
        for (int j = 0; j < 2; ++j)
            acc[i][j] = (floatx4){0.f, 0.f, 0.f, 0.f};

    int lm = lane & 15, q = lane >> 4;

    for (int k0 = 0; k0 < 1024; k0 += 64) {
        __syncthreads();
        #pragma unroll
        for (int i = 0; i < 4; ++i) {          // A tile: 64x64 bf16 = 1024 uint2
            int flat = t + 256 * i;
            int r = flat >> 4, c4 = (flat & 15) * 4;
            *(uint2*)&Asm[r][c4] = *(const uint2*)&A[(size_t)(m0 + r) * 1024 + k0 + c4];
        }
        #pragma unroll
        for (int i = 0; i < 8; ++i) {          // B tile: 128x64 bf16 = 2048 uint2
            int flat = t + 256 * i;
            int r = flat >> 4, c4 = (flat & 15) * 4;
            *(uint2*)&Bsm[r][c4] = *(const uint2*)&Bt[(size_t)(n1 + r) * 1024 + k0 + c4];
        }
        __syncthreads();
        #pragma unroll
        for (int ks = 0; ks < 64; ks += 32) {
            short8 af[4], bfr[2];
            #pragma unroll
            for (int mt = 0; mt < 4; ++mt)
                af[mt] = *(const short8*)&Asm[mt * 16 + lm][ks + q * 8];
            #pragma unroll
            for (int nt = 0; nt < 2; ++nt)
                bfr[nt] = *(const short8*)&Bsm[w * 32 + nt * 16 + lm][ks + q * 8];
            #pragma unroll
            for (int mt = 0; mt < 4; ++mt)
                #pragma unroll
                for (int nt = 0; nt < 2; ++nt)
                    acc[mt][nt] = __builtin_amdgcn_mfma_f32_16x16x32_bf16(af[mt], bfr[nt], acc[mt][nt], 0, 0, 0);
        }
    }
    #pragma unroll
    for (int mt = 0; mt < 4; ++mt)
        #pragma unroll
        for (int nt = 0; nt < 2; ++nt) {
            int col = n1 + w * 32 + nt * 16 + lm;
            float bv = bias[col];
            #pragma unroll
            for (int r = 0; r < 4; ++r) {
                int row = m0 + mt * 16 + q * 4 + r;
                X[(size_t)row * 1024 + col] = acc[mt][nt][r] + bv;
            }
        }
}

// ---------------- K7a: BN stats (sum, sumsq per feature) ----------------
__global__ __launch_bounds__(256) void bnstat_kernel(const float* __restrict__ X,
                                                     float* __restrict__ sums) {
    int f = (blockIdx.x & 3) * 256 + threadIdx.x;
    int rbeg = (blockIdx.x >> 2) * 128;
    float s = 0.f, s2 = 0.f;
    for (int r = 0; r < 128; ++r) {
        float v = X[(size_t)(rbeg + r) * ATT + f];
        s += v; s2 += v * v;
    }
    atomicAdd(&sums[f], s);
    atomicAdd(&sums[ATT + f], s2);
}

// ---------------- K7b: normalize + relu -> d_out ----------------
__global__ __launch_bounds__(256) void bn_kernel(const float* __restrict__ X,
                                                 const float* __restrict__ sums,
                                                 const float* __restrict__ gamma,
                                                 const float* __restrict__ beta,
                                                 float* __restrict__ out) {
    size_t i = (size_t)blockIdx.x * 256 + threadIdx.x;
    int f = (int)(i & 1023);
    float mu = sums[f] * (1.f / BB);
    float var = sums[ATT + f] * (1.f / BB) - mu * mu;
    float v = (X[i] - mu) * rsqrtf(var + 1e-5f) * gamma[f] + beta[f];
    out[i] = v > 0.f ? v : 0.f;
}

extern "C" void kernel_launch(void* const* d_in, const int* in_sizes, int n_in,
                              void* d_out, int out_size, void* d_ws, size_t ws_size,
                              hipStream_t stream) {
    const float* h        = (const float*)d_in[0];
    const float* end_pos  = (const float*)d_in[2];
    const float* rel_pos  = (const float*)d_in[3];
    const float* W_enc    = (const float*)d_in[4];
    const float* b_enc    = (const float*)d_in[5];
    const float* W_dec    = (const float*)d_in[6];
    const float* b_dec    = (const float*)d_in[7];
    const float* w_full   = (const float*)d_in[8];
    const float* b_full   = (const float*)d_in[9];
    const float* W_embed  = (const float*)d_in[10];
    const float* b_embed  = (const float*)d_in[11];
    const float* W_out    = (const float*)d_in[12];
    const float* b_out    = (const float*)d_in[13];
    const float* W_mlp    = (const float*)d_in[14];
    const float* b_mlp    = (const float*)d_in[15];
    const float* bn_gamma = (const float*)d_in[16];
    const float* bn_beta  = (const float*)d_in[17];

    float* ws      = (float*)d_ws;
    // Live layout (floats):
    float* enc     = ws;                         // [0 , 8,388,608) dense enc, nonzero rows only
    float* dec_r   = ws + 8388608;               // [8,388,608 , 10,485,760)
    int*   rowidx  = (int*)(ws + 10485760);      // 131,072 slots
    float* score_c = ws + 10616832;              // 131,072
    float* s_empty = ws + 10747904;              // 2048
    int*   cntA    = (int*)(ws + 10749952);      // 2048
    int*   baseA   = (int*)(ws + 10752000);      // 2048
    int*   counter = (int*)(ws + 10754048);      // 64 (1 used)
    // Aliases into dead regions:
    ushort* out_bf = (ushort*)ws;                // alias enc[0 , 1,048,576) floats = 2048x1024 bf16 (enc dead after K4)
    float*  x      = ws + 1048576;               // alias enc[1,048,576 , 3,145,728) = 2048x1024 fp32
    ushort* Wt     = (ushort*)(ws + 3145728);    // alias enc[3,145,728 , 3,670,016) = 1024x1024 bf16
    float*  ctx_emb= ws + 8388608;               // alias dec_r (dead after K3), 139,264
    float*  sums   = ws + 8527872;               // alias dec_r + 139,264, 2048

    hipMemsetAsync(counter, 0, 64 * sizeof(int), stream);

    pool_kernel<<<BB, 64, 0, stream>>>(h, end_pos, enc, rowidx, cntA, baseA, counter);
    dec_kernel<<<BB, 256, 0, stream>>>(h, W_dec, b_dec, b_enc, w_full, b_full, dec_r, s_empty);
    scoresC_kernel<<<MAXROWS / 64, 256, 0, stream>>>(enc, rowidx, counter, dec_r, W_enc, w_full, b_full, score_c);
    softmax_ctx_kernel<<<BB, 64, 0, stream>>>(score_c, rowidx, cntA, baseA, s_empty, enc,
                                              end_pos, rel_pos, W_embed, b_embed, ctx_emb);
    out_kernel<<<BB, 256, 0, stream>>>(ctx_emb, W_out, b_out, out_bf);
    wt_kernel<<<dim3(16, 16), 256, 0, stream>>>(W_mlp, Wt);
    mlp_mfma_kernel<<<dim3(32, 8), 256, 0, stream>>>(out_bf, Wt, b_mlp, x);
    hipMemsetAsync(sums, 0, 2048 * sizeof(float), stream);
    bnstat_kernel<<<64, 256, 0, stream>>>(x, sums);
    bn_kernel<<<8192, 256, 0, stream>>>(x, sums, bn_gamma, bn_beta, (float*)d_out);
}

// Round 4
// 234.764 us; speedup vs baseline: 2.2665x; 1.2104x over previous
//
#include <hip/hip_runtime.h>
#include <hip/hip_bf16.h>
#include <math.h>

#define H_DIM 64
#define G 64
#define ATT 1024
#define EMB 4
#define P 64
#define BB 2048   // batch B = S*P
#define MAXROWS 129088  // 2048*63 rounded up to multiple of 64

typedef __attribute__((ext_vector_type(8))) short short8;
typedef __attribute__((ext_vector_type(4))) float floatx4;

__device__ inline ushort f2bf(float v) {
    __hip_bfloat16 b = __float2bfloat16(v);
    return *(ushort*)&b;
}
__device__ inline float bf2f(ushort u) {
    union { float f; unsigned u32; } x;
    x.u32 = ((unsigned)u) << 16;
    return x.f;
}

// ---------------- K1: social pooling -> nonzero rows of enc (bf16) + compact row list ----------------
__global__ __launch_bounds__(64) void pool_kernel(const float* __restrict__ h,
                                                  const float* __restrict__ end_pos,
                                                  ushort* __restrict__ enc,
                                                  int* __restrict__ rowidx,
                                                  int* __restrict__ cntA,
                                                  int* __restrict__ baseA,
                                                  int* __restrict__ counter) {
    int b = blockIdx.x;          // anchor index (s*P + i)
    int s = b >> 6;              // P == 64
    int i = b & 63;
    int t = threadIdx.x;         // h-dim lane 0..63
    __shared__ float cell[G][H_DIM];
    #pragma unroll
    for (int g = 0; g < G; ++g) cell[g][t] = 0.f;

    float ax = end_pos[2*b], ay = end_pos[2*b+1];
    float tlx = ax - 1.f, tly = ay + 1.f, brx = ax + 1.f, bry = ay - 1.f;
    const float* hseq = h + (size_t)s * P * H_DIM;
    const float* pseq = end_pos + (size_t)s * P * 2;

    unsigned long long hits = 0ull;   // wave-uniform
    for (int j = 0; j < P; ++j) {
        float ox = pseq[2*j], oy = pseq[2*j+1];
        bool oob = (ox >= brx) || (ox <= tlx) || (oy >= tly) || (oy <= bry) || (j == i);
        if (!oob) {
            int cx = (int)floorf((ox - tlx) / 2.0f * 8.0f);
            int cy = (int)floorf((tly - oy) / 2.0f * 8.0f);
            int g = cx + cy * 8;
            hits |= (1ull << g);
            cell[g][t] += hseq[j * H_DIM + t];
        }
    }
    int n_nz = __popcll(hits);
    int base = 0;
    if (t == 0) base = atomicAdd(counter, n_nz);
    base = __shfl(base, 0);
    if (t == 0) { cntA[b] = n_nz; baseA[b] = base; }

    #pragma unroll 1
    for (int g = 0; g < G; ++g) {
        if ((hits >> g) & 1ull) {  // wave-uniform branch
            int slot = __popcll(hits & ((1ull << g) - 1ull));
            int row = base + slot;
            enc[((size_t)(b * G + g)) * H_DIM + t] = f2bf(cell[g][t]);
            if (t == 0) rowidx[row] = b * G + g;
        }
    }
}

// ---------------- K2: dec_r = h @ W_dec + b_dec + b_enc ; s_empty = relu(dec_r).w_full + b_full ----------------
__global__ __launch_bounds__(256) void dec_kernel(const float* __restrict__ h,
                                                  const float* __restrict__ W,
                                                  const float* __restrict__ b_dec,
                                                  const float* __restrict__ b_enc,
                                                  const float* __restrict__ w_full,
                                                  const float* __restrict__ b_full,
                                                  float* __restrict__ dec_r,
                                                  float* __restrict__ s_empty) {
    int b = blockIdx.x, t = threadIdx.x;
    __shared__ float hS[H_DIM];
    __shared__ float red[256];
    if (t < H_DIM) hS[t] = h[b * H_DIM + t];
    __syncthreads();
    float a0 = 0, a1 = 0, a2 = 0, a3 = 0;
    #pragma unroll 8
    for (int k = 0; k < H_DIM; ++k) {
        float hk = hS[k];
        const float* w = W + (size_t)k * ATT + t;
        a0 += hk * w[0]; a1 += hk * w[256]; a2 += hk * w[512]; a3 += hk * w[768];
    }
    float* o = dec_r + (size_t)b * ATT + t;
    float v0 = a0 + b_dec[t]     + b_enc[t];
    float v1 = a1 + b_dec[t+256] + b_enc[t+256];
    float v2 = a2 + b_dec[t+512] + b_enc[t+512];
    float v3 = a3 + b_dec[t+768] + b_enc[t+768];
    o[0] = v0; o[256] = v1; o[512] = v2; o[768] = v3;
    float sm = fmaxf(v0, 0.f) * w_full[t]     + fmaxf(v1, 0.f) * w_full[t+256]
             + fmaxf(v2, 0.f) * w_full[t+512] + fmaxf(v3, 0.f) * w_full[t+768];
    red[t] = sm;
    __syncthreads();
    for (int off = 128; off > 0; off >>= 1) {
        if (t < off) red[t] += red[t + off];
        __syncthreads();
    }
    if (t == 0) s_empty[b] = red[0] + b_full[0];
}

// ---------------- K2b: Wte[n][k] = bf16(W_enc[k][n])  (64x1024 -> 1024x64) ----------------
__global__ __launch_bounds__(256) void wtenc_kernel(const float* __restrict__ W,
                                                    ushort* __restrict__ Wte) {
    __shared__ float tile[64][65];
    int n0 = blockIdx.x * 64;
    int t = threadIdx.x;
    #pragma unroll
    for (int i = 0; i < 16; ++i) {
        int flat = t + 256 * i;
        int k = flat >> 6, c = flat & 63;
        tile[k][c] = W[(size_t)k * ATT + n0 + c];
    }
    __syncthreads();
    #pragma unroll
    for (int i = 0; i < 16; ++i) {
        int flat = t + 256 * i;
        int n = flat >> 6, k = flat & 63;
        Wte[(size_t)(n0 + n) * 64 + k] = f2bf(tile[k][n]);
    }
}

// ---------------- K3: scores over compact rows (MFMA bf16) ----------------
__global__ __launch_bounds__(256) void scoresC_mfma_kernel(const ushort* __restrict__ enc,
                                                           const int* __restrict__ rowidx,
                                                           const int* __restrict__ counter,
                                                           const float* __restrict__ dec_r,
                                                           const ushort* __restrict__ Wte,
                                                           const float* __restrict__ w_full,
                                                           const float* __restrict__ b_full,
                                                           float* __restrict__ score_c) {
    int M = counter[0];
    int row0 = blockIdx.x * 64;
    if (row0 >= M) return;
    int t = threadIdx.x;
    int w = t >> 6, lane = t & 63;
    int lm = lane & 15, q = lane >> 4;

    __shared__ __align__(16) ushort AS[64][72];    // enc rows [m][k]
    __shared__ __align__(16) ushort BS[256][72];   // W_enc^T chunk [n][k]
    __shared__ int rowS[64];
    __shared__ float redS[4][64];

    if (t < 64) rowS[t] = (row0 + t < M) ? rowidx[row0 + t] : 0;
    __syncthreads();
    #pragma unroll
    for (int i = 0; i < 4; ++i) {           // A: 64 rows x 64 k = 1024 uint2
        int flat = t + 256 * i;
        int r = flat >> 4, c4 = (flat & 15) * 4;
        *(uint2*)&AS[r][c4] = *(const uint2*)&enc[(size_t)rowS[r] * 64 + c4];
    }
    // per-lane row->b mapping for the 16 (mt,r) accumulator rows
    int bbr[16];
    #pragma unroll
    for (int mt = 0; mt < 4; ++mt)
        #pragma unroll
        for (int r = 0; r < 4; ++r)
            bbr[mt * 4 + r] = rowS[mt * 16 + q * 4 + r] >> 6;

    float part[4][4];
    #pragma unroll
    for (int mt = 0; mt < 4; ++mt)
        #pragma unroll
        for (int r = 0; r < 4; ++r) part[mt][r] = 0.f;

    for (int c = 0; c < 4; ++c) {
        __syncthreads();
        #pragma unroll
        for (int i = 0; i < 16; ++i) {      // B: 256 cols x 64 k = 4096 uint2
            int flat = t + 256 * i;
            int r = flat >> 4, c4 = (flat & 15) * 4;
            *(uint2*)&BS[r][c4] = *(const uint2*)&Wte[(size_t)(c * 256 + r) * 64 + c4];
        }
        __syncthreads();

        floatx4 acc[4][4];
        #pragma unroll
        for (int mt = 0; mt < 4; ++mt)
            #pragma unroll
            for (int nt = 0; nt < 4; ++nt) acc[mt][nt] = (floatx4){0.f, 0.f, 0.f, 0.f};

        #pragma unroll
        for (int ks = 0; ks < 64; ks += 32) {
            short8 af[4], bfr[4];
            #pragma unroll
            for (int mt = 0; mt < 4; ++mt)
                af[mt] = *(const short8*)&AS[mt * 16 + lm][ks + q * 8];
            #pragma unroll
            for (int nt = 0; nt < 4; ++nt)
                bfr[nt] = *(const short8*)&BS[w * 64 + nt * 16 + lm][ks + q * 8];
            #pragma unroll
            for (int mt = 0; mt < 4; ++mt)
                #pragma unroll
                for (int nt = 0; nt < 4; ++nt)
                    acc[mt][nt] = __builtin_amdgcn_mfma_f32_16x16x32_bf16(af[mt], bfr[nt], acc[mt][nt], 0, 0, 0);
        }

        int colbase = c * 256 + w * 64;
        #pragma unroll
        for (int nt = 0; nt < 4; ++nt) {
            int col = colbase + nt * 16 + lm;
            float wf = w_full[col];
            #pragma unroll
            for (int mt = 0; mt < 4; ++mt)
                #pragma unroll
                for (int r = 0; r < 4; ++r) {
                    float v = acc[mt][nt][r] + dec_r[(size_t)bbr[mt * 4 + r] * ATT + col];
                    part[mt][r] += fmaxf(v, 0.f) * wf;
                }
        }
    }
    // butterfly sum across the 16 lanes (lm) holding different cols
    #pragma unroll
    for (int mt = 0; mt < 4; ++mt)
        #pragma unroll
        for (int r = 0; r < 4; ++r) {
            float v = part[mt][r];
            v += __shfl_xor(v, 1); v += __shfl_xor(v, 2);
            v += __shfl_xor(v, 4); v += __shfl_xor(v, 8);
            part[mt][r] = v;
        }
    if (lm == 0) {
        #pragma unroll
        for (int mt = 0; mt < 4; ++mt)
            #pragma unroll
            for (int r = 0; r < 4; ++r)
                redS[w][mt * 16 + q * 4 + r] = part[mt][r];
    }
    __syncthreads();
    if (t < 64) {
        int row = row0 + t;
        if (row < M)
            score_c[row] = redS[0][t] + redS[1][t] + redS[2][t] + redS[3][t] + b_full[0];
    }
}

// ---------------- K4: softmax + ctx + emb ----------------
__global__ __launch_bounds__(64) void softmax_ctx_kernel(const float* __restrict__ score_c,
                                                         const int* __restrict__ rowidx,
                                                         const int* __restrict__ cntA,
                                                         const int* __restrict__ baseA,
                                                         const float* __restrict__ s_empty,
                                                         const ushort* __restrict__ enc,
                                                         const float* __restrict__ end_pos,
                                                         const float* __restrict__ rel_pos,
                                                         const float* __restrict__ W_embed,
                                                         const float* __restrict__ b_embed,
                                                         float* __restrict__ ctx_emb) {
    int b = blockIdx.x, t = threadIdx.x;
    int cnt = cntA[b], base = baseA[b];
    float se = s_empty[b];
    float sc = se;
    int ri = 0;
    if (t < cnt) { sc = score_c[base + t]; ri = rowidx[base + t]; }
    float mx = sc;
    #pragma unroll
    for (int o = 32; o > 0; o >>= 1) mx = fmaxf(mx, __shfl_xor(mx, o));
    float e = expf(sc - mx);
    float ssum = e;
    #pragma unroll
    for (int o = 32; o > 0; o >>= 1) ssum += __shfl_xor(ssum, o);
    __shared__ float aS[G];
    __shared__ int rS[G];
    aS[t] = e / ssum;
    rS[t] = ri;
    __syncthreads();
    float ctx = 0.f;
    for (int i = 0; i < cnt; ++i)
        ctx += aS[i] * bf2f(enc[(size_t)rS[i] * H_DIM + t]);
    ctx_emb[(size_t)b * 68 + t] = ctx;
    if (t < EMB) {
        float e0 = end_pos[2*b], e1 = end_pos[2*b+1], e2 = rel_pos[2*b], e3 = rel_pos[2*b+1];
        float v = b_embed[t] + e0 * W_embed[0*EMB + t] + e1 * W_embed[1*EMB + t]
                             + e2 * W_embed[2*EMB + t] + e3 * W_embed[3*EMB + t];
        ctx_emb[(size_t)b * 68 + 64 + t] = v > 0.f ? v : 0.f;
    }
}

// ---------------- K5: out_bf16 = bf16(relu(ctx_emb @ W_out + b_out)) ----------------
__global__ __launch_bounds__(256) void out_kernel(const float* __restrict__ ctx_emb,
                                                  const float* __restrict__ W_out,
                                                  const float* __restrict__ bias,
                                                  ushort* __restrict__ out) {
    int b = blockIdx.x, t = threadIdx.x;
    __shared__ float xS[68];
    if (t < 68) xS[t] = ctx_emb[(size_t)b * 68 + t];
    __syncthreads();
    float a0 = 0, a1 = 0, a2 = 0, a3 = 0;
    #pragma unroll 4
    for (int k = 0; k < 68; ++k) {
        float xk = xS[k];
        const float* w = W_out + (size_t)k * ATT + t;
        a0 += xk * w[0]; a1 += xk * w[256]; a2 += xk * w[512]; a3 += xk * w[768];
    }
    ushort* o = out + (size_t)b * ATT + t;
    o[0]   = f2bf(fmaxf(a0 + bias[t],     0.f));
    o[256] = f2bf(fmaxf(a1 + bias[t+256], 0.f));
    o[512] = f2bf(fmaxf(a2 + bias[t+512], 0.f));
    o[768] = f2bf(fmaxf(a3 + bias[t+768], 0.f));
}

// ---------------- K5b: Wt[n][k] = bf16(W_mlp[k][n]) ----------------
__global__ __launch_bounds__(256) void wt_kernel(const float* __restrict__ Wm,
                                                 ushort* __restrict__ Wt) {
    __shared__ float tile[64][65];
    int k0 = blockIdx.x * 64, n0 = blockIdx.y * 64;
    int t = threadIdx.x;
    #pragma unroll
    for (int i = 0; i < 16; ++i) {
        int flat = t + 256 * i;
        int r = flat >> 6, c = flat & 63;
        tile[r][c] = Wm[(size_t)(k0 + r) * ATT + n0 + c];
    }
    __syncthreads();
    #pragma unroll
    for (int i = 0; i < 16; ++i) {
        int flat = t + 256 * i;
        int r = flat >> 6, c = flat & 63;
        Wt[(size_t)(n0 + r) * ATT + k0 + c] = f2bf(tile[c][r]);
    }
}

// ---------------- K6: x = out_bf16 @ Wt^T + b_mlp  (MFMA, 64x128 block tile) ----------------
__global__ __launch_bounds__(256) void mlp_mfma_kernel(const ushort* __restrict__ A,   // [2048][1024] bf16
                                                       const ushort* __restrict__ Bt,  // [1024 n][1024 k] bf16
                                                       const float* __restrict__ bias,
                                                       float* __restrict__ X) {
    int t = threadIdx.x;
    int w = t >> 6, lane = t & 63;
    int m0 = blockIdx.x * 64, n1 = blockIdx.y * 128;
    __shared__ __align__(16) ushort Asm[64][72];
    __shared__ __align__(16) ushort Bsm[128][72];

    floatx4 acc[4][2];
    #pragma unroll
    for (int i = 0; i < 4; ++i)
        #pragma unroll
        for (int j = 0; j < 2; ++j)
            acc[i][j] = (floatx4){0.f, 0.f, 0.f, 0.f};

    int lm = lane & 15, q = lane >> 4;

    for (int k0 = 0; k0 < 1024; k0 += 64) {
        __syncthreads();
        #pragma unroll
        for (int i = 0; i < 4; ++i) {          // A tile: 64x64 bf16
            int flat = t + 256 * i;
            int r = flat >> 4, c4 = (flat & 15) * 4;
            *(uint2*)&Asm[r][c4] = *(const uint2*)&A[(size_t)(m0 + r) * 1024 + k0 + c4];
        }
        #pragma unroll
        for (int i = 0; i < 8; ++i) {          // B tile: 128x64 bf16
            int flat = t + 256 * i;
            int r = flat >> 4, c4 = (flat & 15) * 4;
            *(uint2*)&Bsm[r][c4] = *(const uint2*)&Bt[(size_t)(n1 + r) * 1024 + k0 + c4];
        }
        __syncthreads();
        #pragma unroll
        for (int ks = 0; ks < 64; ks += 32) {
            short8 af[4], bfr[2];
            #pragma unroll
            for (int mt = 0; mt < 4; ++mt)
                af[mt] = *(const short8*)&Asm[mt * 16 + lm][ks + q * 8];
            #pragma unroll
            for (int nt = 0; nt < 2; ++nt)
                bfr[nt] = *(const short8*)&Bsm[w * 32 + nt * 16 + lm][ks + q * 8];
            #pragma unroll
            for (int mt = 0; mt < 4; ++mt)
                #pragma unroll
                for (int nt = 0; nt < 2; ++nt)
                    acc[mt][nt] = __builtin_amdgcn_mfma_f32_16x16x32_bf16(af[mt], bfr[nt], acc[mt][nt], 0, 0, 0);
        }
    }
    #pragma unroll
    for (int mt = 0; mt < 4; ++mt)
        #pragma unroll
        for (int nt = 0; nt < 2; ++nt) {
            int col = n1 + w * 32 + nt * 16 + lm;
            float bv = bias[col];
            #pragma unroll
            for (int r = 0; r < 4; ++r) {
                int row = m0 + mt * 16 + q * 4 + r;
                X[(size_t)row * 1024 + col] = acc[mt][nt][r] + bv;
            }
        }
}

// ---------------- K7a: BN stats (sum, sumsq per feature) ----------------
__global__ __launch_bounds__(256) void bnstat_kernel(const float* __restrict__ X,
                                                     float* __restrict__ sums) {
    int f = (blockIdx.x & 3) * 256 + threadIdx.x;
    int rbeg = (blockIdx.x >> 2) * 32;
    float s = 0.f, s2 = 0.f;
    for (int r = 0; r < 32; ++r) {
        float v = X[(size_t)(rbeg + r) * ATT + f];
        s += v; s2 += v * v;
    }
    atomicAdd(&sums[f], s);
    atomicAdd(&sums[ATT + f], s2);
}

// ---------------- K7b: normalize + relu -> d_out ----------------
__global__ __launch_bounds__(256) void bn_kernel(const float* __restrict__ X,
                                                 const float* __restrict__ sums,
                                                 const float* __restrict__ gamma,
                                                 const float* __restrict__ beta,
                                                 float* __restrict__ out) {
    size_t i = (size_t)blockIdx.x * 256 + threadIdx.x;
    int f = (int)(i & 1023);
    float mu = sums[f] * (1.f / BB);
    float var = sums[ATT + f] * (1.f / BB) - mu * mu;
    float v = (X[i] - mu) * rsqrtf(var + 1e-5f) * gamma[f] + beta[f];
    out[i] = v > 0.f ? v : 0.f;
}

extern "C" void kernel_launch(void* const* d_in, const int* in_sizes, int n_in,
                              void* d_out, int out_size, void* d_ws, size_t ws_size,
                              hipStream_t stream) {
    const float* h        = (const float*)d_in[0];
    const float* end_pos  = (const float*)d_in[2];
    const float* rel_pos  = (const float*)d_in[3];
    const float* W_enc    = (const float*)d_in[4];
    const float* b_enc    = (const float*)d_in[5];
    const float* W_dec    = (const float*)d_in[6];
    const float* b_dec    = (const float*)d_in[7];
    const float* w_full   = (const float*)d_in[8];
    const float* b_full   = (const float*)d_in[9];
    const float* W_embed  = (const float*)d_in[10];
    const float* b_embed  = (const float*)d_in[11];
    const float* W_out    = (const float*)d_in[12];
    const float* b_out    = (const float*)d_in[13];
    const float* W_mlp    = (const float*)d_in[14];
    const float* b_mlp    = (const float*)d_in[15];
    const float* bn_gamma = (const float*)d_in[16];
    const float* bn_beta  = (const float*)d_in[17];

    float* ws      = (float*)d_ws;
    // Live layout (float-units):
    ushort* enc    = (ushort*)ws;                // [0 , 4,194,304) fl = 131,072 rows x 64 bf16
    ushort* Wte    = (ushort*)(ws + 4194304);    // [4,194,304 , 4,227,072) = 1024x64 bf16
    float* dec_r   = ws + 8388608;               // [8,388,608 , 10,485,760)
    int*   rowidx  = (int*)(ws + 10485760);      // 131,072
    float* score_c = ws + 10616832;              // 131,072
    float* s_empty = ws + 10747904;              // 2048
    int*   cntA    = (int*)(ws + 10749952);      // 2048
    int*   baseA   = (int*)(ws + 10752000);      // 2048
    int*   counter = (int*)(ws + 10754048);      // 64 (1 used)
    // Aliases into dead regions (after K4):
    ushort* out_bf = (ushort*)ws;                // [0 , 1,048,576) fl = 2048x1024 bf16
    float*  x      = ws + 1048576;               // [1,048,576 , 3,145,728) = 2048x1024 fp32
    ushort* Wt     = (ushort*)(ws + 3145728);    // [3,145,728 , 3,670,016) = 1024x1024 bf16
    float*  ctx_emb= ws + 8388608;               // alias dec_r (dead after K3), 139,264
    float*  sums   = ws + 8527872;               // alias dec_r + 139,264, 2048

    hipMemsetAsync(counter, 0, 64 * sizeof(int), stream);

    pool_kernel<<<BB, 64, 0, stream>>>(h, end_pos, enc, rowidx, cntA, baseA, counter);
    wtenc_kernel<<<16, 256, 0, stream>>>(W_enc, Wte);
    dec_kernel<<<BB, 256, 0, stream>>>(h, W_dec, b_dec, b_enc, w_full, b_full, dec_r, s_empty);
    scoresC_mfma_kernel<<<MAXROWS / 64, 256, 0, stream>>>(enc, rowidx, counter, dec_r, Wte,
                                                          w_full, b_full, score_c);
    softmax_ctx_kernel<<<BB, 64, 0, stream>>>(score_c, rowidx, cntA, baseA, s_empty, enc,
                                              end_pos, rel_pos, W_embed, b_embed, ctx_emb);
    out_kernel<<<BB, 256, 0, stream>>>(ctx_emb, W_out, b_out, out_bf);
    wt_kernel<<<dim3(16, 16), 256, 0, stream>>>(W_mlp, Wt);
    mlp_mfma_kernel<<<dim3(32, 8), 256, 0, stream>>>(out_bf, Wt, b_mlp, x);
    hipMemsetAsync(sums, 0, 2048 * sizeof(float), stream);
    bnstat_kernel<<<256, 256, 0, stream>>>(x, sums);
    bn_kernel<<<8192, 256, 0, stream>>>(x, sums, bn_gamma, bn_beta, (float*)d_out);
}

// Round 5
// 202.140 us; speedup vs baseline: 2.6323x; 1.1614x over previous
//
#include <hip/hip_runtime.h>
#include <hip/hip_bf16.h>
#include <math.h>

#define H_DIM 64
#define G 64
#define ATT 1024
#define EMB 4
#define P 64
#define BB 2048   // batch B = S*P
#define MAXROWS 129088  // 2048*63 rounded up to multiple of 64
#define PREP_BLOCKS (2048 + 16 + 16 + 16 + 256)

typedef __attribute__((ext_vector_type(8))) short short8;
typedef __attribute__((ext_vector_type(4))) float floatx4;

__device__ inline ushort f2bf(float v) {
    __hip_bfloat16 b = __float2bfloat16(v);
    return *(ushort*)&b;
}
__device__ inline float bf2f(ushort u) {
    union { float f; unsigned u32; } x;
    x.u32 = ((unsigned)u) << 16;
    return x.f;
}

// ---------------- K1: prep = pool(+h->bf16) | W_enc^T | W_dec^T | W_out^T(pad96) | W_mlp^T ----------------
__global__ __launch_bounds__(256) void prep_kernel(const float* __restrict__ h,
                                                   const float* __restrict__ end_pos,
                                                   const float* __restrict__ W_enc,
                                                   const float* __restrict__ W_dec,
                                                   const float* __restrict__ W_out,
                                                   const float* __restrict__ W_mlp,
                                                   ushort* __restrict__ enc,
                                                   ushort* __restrict__ h_bf,
                                                   ushort* __restrict__ Wte,
                                                   ushort* __restrict__ Wdt,
                                                   ushort* __restrict__ Wot,
                                                   ushort* __restrict__ Wt,
                                                   int* __restrict__ rowidx,
                                                   int* __restrict__ cntA,
                                                   int* __restrict__ baseA,
                                                   int* __restrict__ counter) {
    __shared__ float cellp[2][G][H_DIM];   // 32 KB
    __shared__ float tileT[64][65];        // 16.25 KB (transpose branches)
    __shared__ unsigned long long hitsS[2];
    __shared__ int baseS;

    int blk = blockIdx.x;
    int t = threadIdx.x;

    if (blk < 2048) {
        // ---- social pooling, one anchor per block, 2-wave split accumulation ----
        int b = blk, s = b >> 6, i = b & 63;
        int w = t >> 6, lane = t & 63;
        float* cp = &cellp[0][0][0];
        #pragma unroll
        for (int idx = 0; idx < 8; ++idx)
            *(float4*)&cp[(t + 256 * idx) * 4] = (float4){0.f, 0.f, 0.f, 0.f};
        if (w == 3) h_bf[(size_t)b * 64 + lane] = f2bf(h[(size_t)b * 64 + lane]);
        __syncthreads();

        float ax = end_pos[2 * b], ay = end_pos[2 * b + 1];
        float tlx = ax - 1.f, tly = ay + 1.f, brx = ax + 1.f, bry = ay - 1.f;
        const float* hseq = h + (size_t)s * P * H_DIM;
        const float* pseq = end_pos + (size_t)s * P * 2;

        if (w < 2) {
            unsigned long long hits = 0ull;
            for (int jj = 0; jj < 32; ++jj) {
                int j = w * 32 + jj;
                float ox = pseq[2 * j], oy = pseq[2 * j + 1];
                bool oob = (ox >= brx) || (ox <= tlx) || (oy >= tly) || (oy <= bry) || (j == i);
                if (!oob) {
                    int cx = (int)floorf((ox - tlx) / 2.0f * 8.0f);
                    int cy = (int)floorf((tly - oy) / 2.0f * 8.0f);
                    int g = cx + cy * 8;
                    hits |= (1ull << g);
                    cellp[w][g][lane] += hseq[j * H_DIM + lane];
                }
            }
            if (lane == 0) hitsS[w] = hits;
        }
        __syncthreads();
        unsigned long long uh = hitsS[0] | hitsS[1];
        int n_nz = __popcll(uh);
        if (t == 0) {
            int bs = atomicAdd(counter, n_nz);
            baseS = bs; cntA[b] = n_nz; baseA[b] = bs;
        }
        __syncthreads();
        int base = baseS;
        for (int g = w; g < 64; g += 4) {
            if ((uh >> g) & 1ull) {
                int slot = __popcll(uh & ((1ull << g) - 1ull));
                enc[((size_t)(b * G + g)) * H_DIM + lane] =
                    f2bf(cellp[0][g][lane] + cellp[1][g][lane]);
                if (lane == 0) rowidx[base + slot] = b * G + g;
            }
        }
    } else if (blk < 2064) {
        // ---- Wte[n][k] = bf16(W_enc[k][n]), 64x1024 -> 1024x64 ----
        int n0 = (blk - 2048) * 64;
        #pragma unroll
        for (int idx = 0; idx < 16; ++idx) {
            int flat = t + 256 * idx;
            int k = flat >> 6, c = flat & 63;
            tileT[k][c] = W_enc[(size_t)k * ATT + n0 + c];
        }
        __syncthreads();
        #pragma unroll
        for (int idx = 0; idx < 16; ++idx) {
            int flat = t + 256 * idx;
            int n = flat >> 6, k = flat & 63;
            Wte[(size_t)(n0 + n) * 64 + k] = f2bf(tileT[k][n]);
        }
    } else if (blk < 2080) {
        // ---- Wdt[n][k] = bf16(W_dec[k][n]) ----
        int n0 = (blk - 2064) * 64;
        #pragma unroll
        for (int idx = 0; idx < 16; ++idx) {
            int flat = t + 256 * idx;
            int k = flat >> 6, c = flat & 63;
            tileT[k][c] = W_dec[(size_t)k * ATT + n0 + c];
        }
        __syncthreads();
        #pragma unroll
        for (int idx = 0; idx < 16; ++idx) {
            int flat = t + 256 * idx;
            int n = flat >> 6, k = flat & 63;
            Wdt[(size_t)(n0 + n) * 64 + k] = f2bf(tileT[k][n]);
        }
    } else if (blk < 2096) {
        // ---- Wot[n][k] = bf16(W_out[k][n]) for k<68 else 0, layout 1024x96 ----
        int n0 = (blk - 2080) * 64;
        int n = t & 63, kg = t >> 6;
        #pragma unroll
        for (int kk = 0; kk < 24; ++kk) {
            int k = kg * 24 + kk;
            float v = (k < 68) ? W_out[(size_t)k * ATT + n0 + n] : 0.f;
            Wot[(size_t)(n0 + n) * 96 + k] = f2bf(v);
        }
    } else {
        // ---- Wt[n][k] = bf16(W_mlp[k][n]), 1024x1024 in 64x64 tiles ----
        int idx2 = blk - 2096;
        int k0 = (idx2 & 15) * 64, n0 = (idx2 >> 4) * 64;
        #pragma unroll
        for (int idx = 0; idx < 16; ++idx) {
            int flat = t + 256 * idx;
            int r = flat >> 6, c = flat & 63;
            tileT[r][c] = W_mlp[(size_t)(k0 + r) * ATT + n0 + c];
        }
        __syncthreads();
        #pragma unroll
        for (int idx = 0; idx < 16; ++idx) {
            int flat = t + 256 * idx;
            int r = flat >> 6, c = flat & 63;
            Wt[(size_t)(n0 + r) * ATT + k0 + c] = f2bf(tileT[c][r]);
        }
    }
}

// ---------------- K2: dec_r = h_bf @ Wdt^T + b_dec + b_enc (MFMA) ; s_empty += relu(v).w_full ----------------
__global__ __launch_bounds__(256) void dec_mfma_kernel(const ushort* __restrict__ A,   // h_bf [2048][64]
                                                       const ushort* __restrict__ Bt,  // Wdt [1024][64]
                                                       const float* __restrict__ b_dec,
                                                       const float* __restrict__ b_enc,
                                                       const float* __restrict__ w_full,
                                                       float* __restrict__ dec_r,
                                                       float* __restrict__ s_empty) {
    int t = threadIdx.x;
    int w = t >> 6, lane = t & 63;
    int lm = lane & 15, q = lane >> 4;
    int m0 = blockIdx.x * 64, n1 = blockIdx.y * 128;
    __shared__ __align__(16) ushort Asm[64][72];
    __shared__ __align__(16) ushort Bsm[128][72];

    #pragma unroll
    for (int i = 0; i < 4; ++i) {
        int flat = t + 256 * i;
        int r = flat >> 4, c4 = (flat & 15) * 4;
        *(uint2*)&Asm[r][c4] = *(const uint2*)&A[(size_t)(m0 + r) * 64 + c4];
    }
    #pragma unroll
    for (int i = 0; i < 8; ++i) {
        int flat = t + 256 * i;
        int r = flat >> 4, c4 = (flat & 15) * 4;
        *(uint2*)&Bsm[r][c4] = *(const uint2*)&Bt[(size_t)(n1 + r) * 64 + c4];
    }
    __syncthreads();

    floatx4 acc[4][2];
    #pragma unroll
    for (int mt = 0; mt < 4; ++mt)
        #pragma unroll
        for (int nt = 0; nt < 2; ++nt) acc[mt][nt] = (floatx4){0.f, 0.f, 0.f, 0.f};

    #pragma unroll
    for (int ks = 0; ks < 64; ks += 32) {
        short8 af[4], bfr[2];
        #pragma unroll
        for (int mt = 0; mt < 4; ++mt)
            af[mt] = *(const short8*)&Asm[mt * 16 + lm][ks + q * 8];
        #pragma unroll
        for (int nt = 0; nt < 2; ++nt)
            bfr[nt] = *(const short8*)&Bsm[w * 32 + nt * 16 + lm][ks + q * 8];
        #pragma unroll
        for (int mt = 0; mt < 4; ++mt)
            #pragma unroll
            for (int nt = 0; nt < 2; ++nt)
                acc[mt][nt] = __builtin_amdgcn_mfma_f32_16x16x32_bf16(af[mt], bfr[nt], acc[mt][nt], 0, 0, 0);
    }

    float part[4][4];
    #pragma unroll
    for (int mt = 0; mt < 4; ++mt)
        #pragma unroll
        for (int r = 0; r < 4; ++r) part[mt][r] = 0.f;

    #pragma unroll
    for (int nt = 0; nt < 2; ++nt) {
        int col = n1 + w * 32 + nt * 16 + lm;
        float bcol = b_dec[col] + b_enc[col];
        float wf = w_full[col];
        #pragma unroll
        for (int mt = 0; mt < 4; ++mt)
            #pragma unroll
            for (int r = 0; r < 4; ++r) {
                int row = m0 + mt * 16 + q * 4 + r;
                float v = acc[mt][nt][r] + bcol;
                dec_r[(size_t)row * ATT + col] = v;
                part[mt][r] += fmaxf(v, 0.f) * wf;
            }
    }
    #pragma unroll
    for (int mt = 0; mt < 4; ++mt)
        #pragma unroll
        for (int r = 0; r < 4; ++r) {
            float v = part[mt][r];
            v += __shfl_xor(v, 1); v += __shfl_xor(v, 2);
            v += __shfl_xor(v, 4); v += __shfl_xor(v, 8);
            part[mt][r] = v;
        }
    if (lm == 0) {
        #pragma unroll
        for (int mt = 0; mt < 4; ++mt)
            #pragma unroll
            for (int r = 0; r < 4; ++r)
                atomicAdd(&s_empty[m0 + mt * 16 + q * 4 + r], part[mt][r]);
    }
}

// ---------------- K3: scores over compact rows (MFMA bf16) ----------------
__global__ __launch_bounds__(256) void scoresC_mfma_kernel(const ushort* __restrict__ enc,
                                                           const int* __restrict__ rowidx,
                                                           const int* __restrict__ counter,
                                                           const float* __restrict__ dec_r,
                                                           const ushort* __restrict__ Wte,
                                                           const float* __restrict__ w_full,
                                                           const float* __restrict__ b_full,
                                                           float* __restrict__ score_c) {
    int M = counter[0];
    int row0 = blockIdx.x * 64;
    if (row0 >= M) return;
    int t = threadIdx.x;
    int w = t >> 6, lane = t & 63;
    int lm = lane & 15, q = lane >> 4;

    __shared__ __align__(16) ushort AS[64][72];    // enc rows [m][k]
    __shared__ __align__(16) ushort BS[256][72];   // W_enc^T chunk [n][k]
    __shared__ int rowS[64];
    __shared__ float redS[4][64];

    if (t < 64) rowS[t] = (row0 + t < M) ? rowidx[row0 + t] : 0;
    __syncthreads();
    #pragma unroll
    for (int i = 0; i < 4; ++i) {
        int flat = t + 256 * i;
        int r = flat >> 4, c4 = (flat & 15) * 4;
        *(uint2*)&AS[r][c4] = *(const uint2*)&enc[(size_t)rowS[r] * 64 + c4];
    }
    int bbr[16];
    #pragma unroll
    for (int mt = 0; mt < 4; ++mt)
        #pragma unroll
        for (int r = 0; r < 4; ++r)
            bbr[mt * 4 + r] = rowS[mt * 16 + q * 4 + r] >> 6;

    float part[4][4];
    #pragma unroll
    for (int mt = 0; mt < 4; ++mt)
        #pragma unroll
        for (int r = 0; r < 4; ++r) part[mt][r] = 0.f;

    for (int c = 0; c < 4; ++c) {
        __syncthreads();
        #pragma unroll
        for (int i = 0; i < 16; ++i) {
            int flat = t + 256 * i;
            int r = flat >> 4, c4 = (flat & 15) * 4;
            *(uint2*)&BS[r][c4] = *(const uint2*)&Wte[(size_t)(c * 256 + r) * 64 + c4];
        }
        __syncthreads();

        floatx4 acc[4][4];
        #pragma unroll
        for (int mt = 0; mt < 4; ++mt)
            #pragma unroll
            for (int nt = 0; nt < 4; ++nt) acc[mt][nt] = (floatx4){0.f, 0.f, 0.f, 0.f};

        #pragma unroll
        for (int ks = 0; ks < 64; ks += 32) {
            short8 af[4], bfr[4];
            #pragma unroll
            for (int mt = 0; mt < 4; ++mt)
                af[mt] = *(const short8*)&AS[mt * 16 + lm][ks + q * 8];
            #pragma unroll
            for (int nt = 0; nt < 4; ++nt)
                bfr[nt] = *(const short8*)&BS[w * 64 + nt * 16 + lm][ks + q * 8];
            #pragma unroll
            for (int mt = 0; mt < 4; ++mt)
                #pragma unroll
                for (int nt = 0; nt < 4; ++nt)
                    acc[mt][nt] = __builtin_amdgcn_mfma_f32_16x16x32_bf16(af[mt], bfr[nt], acc[mt][nt], 0, 0, 0);
        }

        int colbase = c * 256 + w * 64;
        #pragma unroll
        for (int nt = 0; nt < 4; ++nt) {
            int col = colbase + nt * 16 + lm;
            float wf = w_full[col];
            #pragma unroll
            for (int mt = 0; mt < 4; ++mt)
                #pragma unroll
                for (int r = 0; r < 4; ++r) {
                    float v = acc[mt][nt][r] + dec_r[(size_t)bbr[mt * 4 + r] * ATT + col];
                    part[mt][r] += fmaxf(v, 0.f) * wf;
                }
        }
    }
    #pragma unroll
    for (int mt = 0; mt < 4; ++mt)
        #pragma unroll
        for (int r = 0; r < 4; ++r) {
            float v = part[mt][r];
            v += __shfl_xor(v, 1); v += __shfl_xor(v, 2);
            v += __shfl_xor(v, 4); v += __shfl_xor(v, 8);
            part[mt][r] = v;
        }
    if (lm == 0) {
        #pragma unroll
        for (int mt = 0; mt < 4; ++mt)
            #pragma unroll
            for (int r = 0; r < 4; ++r)
                redS[w][mt * 16 + q * 4 + r] = part[mt][r];
    }
    __syncthreads();
    if (t < 64) {
        int row = row0 + t;
        if (row < M)
            score_c[row] = redS[0][t] + redS[1][t] + redS[2][t] + redS[3][t] + b_full[0];
    }
}

// ---------------- K4: softmax + ctx + emb -> ctx_bf[2048][96] (bf16, zero-padded) ----------------
__global__ __launch_bounds__(64) void softmax_ctx_kernel(const float* __restrict__ score_c,
                                                         const int* __restrict__ rowidx,
                                                         const int* __restrict__ cntA,
                                                         const int* __restrict__ baseA,
                                                         const float* __restrict__ s_empty,
                                                         const ushort* __restrict__ enc,
                                                         const float* __restrict__ end_pos,
                                                         const float* __restrict__ rel_pos,
                                                         const float* __restrict__ W_embed,
                                                         const float* __restrict__ b_embed,
                                                         const float* __restrict__ b_full,
                                                         ushort* __restrict__ ctx_bf) {
    int b = blockIdx.x, t = threadIdx.x;
    int cnt = cntA[b], base = baseA[b];
    float se = s_empty[b] + b_full[0];
    float sc = se;
    int ri = 0;
    if (t < cnt) { sc = score_c[base + t]; ri = rowidx[base + t]; }
    float mx = sc;
    #pragma unroll
    for (int o = 32; o > 0; o >>= 1) mx = fmaxf(mx, __shfl_xor(mx, o));
    float e = expf(sc - mx);
    float ssum = e;
    #pragma unroll
    for (int o = 32; o > 0; o >>= 1) ssum += __shfl_xor(ssum, o);
    __shared__ float aS[G];
    __shared__ int rS[G];
    aS[t] = e / ssum;
    rS[t] = ri;
    __syncthreads();
    float ctx = 0.f;
    for (int i = 0; i < cnt; ++i)
        ctx += aS[i] * bf2f(enc[(size_t)rS[i] * H_DIM + t]);
    ctx_bf[(size_t)b * 96 + t] = f2bf(ctx);
    if (t < EMB) {
        float e0 = end_pos[2*b], e1 = end_pos[2*b+1], e2 = rel_pos[2*b], e3 = rel_pos[2*b+1];
        float v = b_embed[t] + e0 * W_embed[0*EMB + t] + e1 * W_embed[1*EMB + t]
                             + e2 * W_embed[2*EMB + t] + e3 * W_embed[3*EMB + t];
        ctx_bf[(size_t)b * 96 + 64 + t] = f2bf(v > 0.f ? v : 0.f);
    }
    if (t < 28) ctx_bf[(size_t)b * 96 + 68 + t] = 0;
}

// ---------------- K5: out_bf = bf16(relu(ctx_bf @ Wot^T + b_out))  (MFMA, K=96) ----------------
__global__ __launch_bounds__(256) void out_mfma_kernel(const ushort* __restrict__ A,   // ctx_bf [2048][96]
                                                       const ushort* __restrict__ Bt,  // Wot [1024][96]
                                                       const float* __restrict__ bias,
                                                       ushort* __restrict__ out) {
    int t = threadIdx.x;
    int w = t >> 6, lane = t & 63;
    int lm = lane & 15, q = lane >> 4;
    int m0 = blockIdx.x * 64, n1 = blockIdx.y * 128;
    __shared__ __align__(16) ushort Asm[64][104];
    __shared__ __align__(16) ushort Bsm[128][104];

    {   // A: 64 rows x 96 ush = 12 uint4/row; 4 threads/row x 3 each
        int r = t >> 2, pp = t & 3;
        #pragma unroll
        for (int ii = 0; ii < 3; ++ii) {
            int c8 = (pp * 3 + ii) * 8;
            *(uint4*)&Asm[r][c8] = *(const uint4*)&A[(size_t)(m0 + r) * 96 + c8];
        }
    }
    {   // B: 128 rows x 96 ush; 2 threads/row x 6 each
        int r = t >> 1, pp = t & 1;
        #pragma unroll
        for (int ii = 0; ii < 6; ++ii) {
            int c8 = (pp * 6 + ii) * 8;
            *(uint4*)&Bsm[r][c8] = *(const uint4*)&Bt[(size_t)(n1 + r) * 96 + c8];
        }
    }
    __syncthreads();

    floatx4 acc[4][2];
    #pragma unroll
    for (int mt = 0; mt < 4; ++mt)
        #pragma unroll
        for (int nt = 0; nt < 2; ++nt) acc[mt][nt] = (floatx4){0.f, 0.f, 0.f, 0.f};

    #pragma unroll
    for (int ks = 0; ks < 96; ks += 32) {
        short8 af[4], bfr[2];
        #pragma unroll
        for (int mt = 0; mt < 4; ++mt)
            af[mt] = *(const short8*)&Asm[mt * 16 + lm][ks + q * 8];
        #pragma unroll
        for (int nt = 0; nt < 2; ++nt)
            bfr[nt] = *(const short8*)&Bsm[w * 32 + nt * 16 + lm][ks + q * 8];
        #pragma unroll
        for (int mt = 0; mt < 4; ++mt)
            #pragma unroll
            for (int nt = 0; nt < 2; ++nt)
                acc[mt][nt] = __builtin_amdgcn_mfma_f32_16x16x32_bf16(af[mt], bfr[nt], acc[mt][nt], 0, 0, 0);
    }
    #pragma unroll
    for (int nt = 0; nt < 2; ++nt) {
        int col = n1 + w * 32 + nt * 16 + lm;
        float bv = bias[col];
        #pragma unroll
        for (int mt = 0; mt < 4; ++mt)
            #pragma unroll
            for (int r = 0; r < 4; ++r) {
                int row = m0 + mt * 16 + q * 4 + r;
                out[(size_t)row * ATT + col] = f2bf(fmaxf(acc[mt][nt][r] + bv, 0.f));
            }
    }
}

// ---------------- K6: x = out_bf @ Wt^T + b_mlp (MFMA) + fused BN stats ----------------
__global__ __launch_bounds__(256) void mlp_mfma_kernel(const ushort* __restrict__ A,   // [2048][1024] bf16
                                                       const ushort* __restrict__ Bt,  // [1024][1024] bf16
                                                       const float* __restrict__ bias,
                                                       float* __restrict__ X,
                                                       float* __restrict__ sums) {
    int t = threadIdx.x;
    int w = t >> 6, lane = t & 63;
    int lm = lane & 15, q = lane >> 4;
    int m0 = blockIdx.x * 64, n1 = blockIdx.y * 128;
    __shared__ __align__(16) ushort Asm[64][72];
    __shared__ __align__(16) ushort Bsm[128][72];

    floatx4 acc[4][2];
    #pragma unroll
    for (int mt = 0; mt < 4; ++mt)
        #pragma unroll
        for (int nt = 0; nt < 2; ++nt) acc[mt][nt] = (floatx4){0.f, 0.f, 0.f, 0.f};

    for (int k0 = 0; k0 < 1024; k0 += 64) {
        __syncthreads();
        #pragma unroll
        for (int i = 0; i < 4; ++i) {
            int flat = t + 256 * i;
            int r = flat >> 4, c4 = (flat & 15) * 4;
            *(uint2*)&Asm[r][c4] = *(const uint2*)&A[(size_t)(m0 + r) * 1024 + k0 + c4];
        }
        #pragma unroll
        for (int i = 0; i < 8; ++i) {
            int flat = t + 256 * i;
            int r = flat >> 4, c4 = (flat & 15) * 4;
            *(uint2*)&Bsm[r][c4] = *(const uint2*)&Bt[(size_t)(n1 + r) * 1024 + k0 + c4];
        }
        __syncthreads();
        #pragma unroll
        for (int ks = 0; ks < 64; ks += 32) {
            short8 af[4], bfr[2];
            #pragma unroll
            for (int mt = 0; mt < 4; ++mt)
                af[mt] = *(const short8*)&Asm[mt * 16 + lm][ks + q * 8];
            #pragma unroll
            for (int nt = 0; nt < 2; ++nt)
                bfr[nt] = *(const short8*)&Bsm[w * 32 + nt * 16 + lm][ks + q * 8];
            #pragma unroll
            for (int mt = 0; mt < 4; ++mt)
                #pragma unroll
                for (int nt = 0; nt < 2; ++nt)
                    acc[mt][nt] = __builtin_amdgcn_mfma_f32_16x16x32_bf16(af[mt], bfr[nt], acc[mt][nt], 0, 0, 0);
        }
    }
    #pragma unroll
    for (int nt = 0; nt < 2; ++nt) {
        int col = n1 + w * 32 + nt * 16 + lm;
        float bv = bias[col];
        float s1 = 0.f, s2 = 0.f;
        #pragma unroll
        for (int mt = 0; mt < 4; ++mt)
            #pragma unroll
            for (int r = 0; r < 4; ++r) {
                int row = m0 + mt * 16 + q * 4 + r;
                float v = acc[mt][nt][r] + bv;
                X[(size_t)row * 1024 + col] = v;
                s1 += v; s2 += v * v;
            }
        s1 += __shfl_xor(s1, 16); s1 += __shfl_xor(s1, 32);
        s2 += __shfl_xor(s2, 16); s2 += __shfl_xor(s2, 32);
        if (q == 0) {
            atomicAdd(&sums[col], s1);
            atomicAdd(&sums[ATT + col], s2);
        }
    }
}

// ---------------- K7: normalize + relu -> d_out ----------------
__global__ __launch_bounds__(256) void bn_kernel(const float* __restrict__ X,
                                                 const float* __restrict__ sums,
                                                 const float* __restrict__ gamma,
                                                 const float* __restrict__ beta,
                                                 float* __restrict__ out) {
    size_t i = (size_t)blockIdx.x * 256 + threadIdx.x;
    int f = (int)(i & 1023);
    float mu = sums[f] * (1.f / BB);
    float var = sums[ATT + f] * (1.f / BB) - mu * mu;
    float v = (X[i] - mu) * rsqrtf(var + 1e-5f) * gamma[f] + beta[f];
    out[i] = v > 0.f ? v : 0.f;
}

extern "C" void kernel_launch(void* const* d_in, const int* in_sizes, int n_in,
                              void* d_out, int out_size, void* d_ws, size_t ws_size,
                              hipStream_t stream) {
    const float* h        = (const float*)d_in[0];
    const float* end_pos  = (const float*)d_in[2];
    const float* rel_pos  = (const float*)d_in[3];
    const float* W_enc    = (const float*)d_in[4];
    const float* b_enc    = (const float*)d_in[5];
    const float* W_dec    = (const float*)d_in[6];
    const float* b_dec    = (const float*)d_in[7];
    const float* w_full   = (const float*)d_in[8];
    const float* b_full   = (const float*)d_in[9];
    const float* W_embed  = (const float*)d_in[10];
    const float* b_embed  = (const float*)d_in[11];
    const float* W_out    = (const float*)d_in[12];
    const float* b_out    = (const float*)d_in[13];
    const float* W_mlp    = (const float*)d_in[14];
    const float* b_mlp    = (const float*)d_in[15];
    const float* bn_gamma = (const float*)d_in[16];
    const float* bn_beta  = (const float*)d_in[17];

    float* ws = (float*)d_ws;
    // Layout (float-unit offsets), no aliasing:
    ushort* enc     = (ushort*)ws;                 // 131072 x 64 bf16  -> [0, 4,194,304)
    ushort* h_bf    = (ushort*)(ws + 4194304);     // 2048 x 64 bf16    (65,536 fl)
    ushort* Wte     = (ushort*)(ws + 4259840);     // 1024 x 64 bf16    (32,768 fl)
    ushort* Wdt     = (ushort*)(ws + 4292608);     // 1024 x 64 bf16    (32,768 fl)
    ushort* Wot     = (ushort*)(ws + 4325376);     // 1024 x 96 bf16    (49,152 fl)
    ushort* Wt      = (ushort*)(ws + 4374528);     // 1024 x 1024 bf16  (524,288 fl)
    ushort* ctx_bf  = (ushort*)(ws + 4898816);     // 2048 x 96 bf16    (98,304 fl)
    ushort* out_bf  = (ushort*)(ws + 4997120);     // 2048 x 1024 bf16  (1,048,576 fl)
    float*  x       = ws + 6045696;                // 2048 x 1024 fp32  (2,097,152 fl)
    float*  dec_r   = ws + 8388608;                // 2048 x 1024 fp32  (2,097,152 fl)
    int*    rowidx  = (int*)(ws + 10485760);       // 131,072
    float*  score_c = ws + 10616832;               // 131,072
    int*    cntA    = (int*)(ws + 10747904);       // 2,048
    int*    baseA   = (int*)(ws + 10749952);       // 2,048
    // zero block: counter(64) + s_empty(2048) + sums(2048)
    int*    counter = (int*)(ws + 10752000);
    float*  s_empty = ws + 10752064;
    float*  sums    = ws + 10754112;

    hipMemsetAsync(counter, 0, (64 + 2048 + 2048) * sizeof(float), stream);

    prep_kernel<<<PREP_BLOCKS, 256, 0, stream>>>(h, end_pos, W_enc, W_dec, W_out, W_mlp,
                                                 enc, h_bf, Wte, Wdt, Wot, Wt,
                                                 rowidx, cntA, baseA, counter);
    dec_mfma_kernel<<<dim3(32, 8), 256, 0, stream>>>(h_bf, Wdt, b_dec, b_enc, w_full, dec_r, s_empty);
    scoresC_mfma_kernel<<<MAXROWS / 64, 256, 0, stream>>>(enc, rowidx, counter, dec_r, Wte,
                                                          w_full, b_full, score_c);
    softmax_ctx_kernel<<<BB, 64, 0, stream>>>(score_c, rowidx, cntA, baseA, s_empty, enc,
                                              end_pos, rel_pos, W_embed, b_embed, b_full, ctx_bf);
    out_mfma_kernel<<<dim3(32, 8), 256, 0, stream>>>(ctx_bf, Wot, b_out, out_bf);
    mlp_mfma_kernel<<<dim3(32, 8), 256, 0, stream>>>(out_bf, Wt, b_mlp, x, sums);
    bn_kernel<<<8192, 256, 0, stream>>>(x, sums, bn_gamma, bn_beta, (float*)d_out);
}

// Round 6
// 195.741 us; speedup vs baseline: 2.7184x; 1.0327x over previous
//
#include <hip/hip_runtime.h>
#include <hip/hip_bf16.h>
#include <math.h>

#define H_DIM 64
#define G 64
#define ATT 1024
#define EMB 4
#define P 64
#define BB 2048   // batch B = S*P
#define MAXROWS 129088  // 2048*63 rounded up to multiple of 64
#define PREP_BLOCKS (512 + 16 + 16 + 16 + 256)

typedef __attribute__((ext_vector_type(8))) short short8;
typedef __attribute__((ext_vector_type(4))) float floatx4;

__device__ inline ushort f2bf(float v) {
    __hip_bfloat16 b = __float2bfloat16(v);
    return *(ushort*)&b;
}
__device__ inline float bf2f(ushort u) {
    union { float f; unsigned u32; } x;
    x.u32 = ((unsigned)u) << 16;
    return x.f;
}

// ---------------- K1: prep = pool(+h->bf16) | W_enc^T | W_dec^T | W_out^T(pad96) | W_mlp^T ----------------
// Pool: one wave per anchor, ballot-based, no LDS, ~12 serial iterations.
__global__ __launch_bounds__(256) void prep_kernel(const float* __restrict__ h,
                                                   const float* __restrict__ end_pos,
                                                   const float* __restrict__ W_enc,
                                                   const float* __restrict__ W_dec,
                                                   const float* __restrict__ W_out,
                                                   const float* __restrict__ W_mlp,
                                                   ushort* __restrict__ enc,
                                                   ushort* __restrict__ h_bf,
                                                   ushort* __restrict__ Wte,
                                                   ushort* __restrict__ Wdt,
                                                   ushort* __restrict__ Wot,
                                                   ushort* __restrict__ Wt,
                                                   int* __restrict__ rowidx,
                                                   int* __restrict__ cntA,
                                                   int* __restrict__ baseA,
                                                   int* __restrict__ counter) {
    __shared__ float tileT[64][65];        // transpose branches only (16.25 KB)

    int blk = blockIdx.x;
    int t = threadIdx.x;

    if (blk < 512) {
        // ---- social pooling: wave wv handles anchor b = blk*4+wv ----
        int wv = t >> 6, lane = t & 63;
        int b = blk * 4 + wv;
        int s = b >> 6, i = b & 63;
        const float* pseq = end_pos + (size_t)s * P * 2;
        const float* hrow = h + (size_t)s * P * H_DIM;

        // lane j = this wave's peer j
        float2 pj = ((const float2*)pseq)[lane];
        float ax = __shfl(pj.x, i), ay = __shfl(pj.y, i);
        float tlx = ax - 1.f, tly = ay + 1.f, brx = ax + 1.f, bry = ay - 1.f;
        bool oob = (pj.x >= brx) || (pj.x <= tlx) || (pj.y >= tly) || (pj.y <= bry) || (lane == i);
        int cx = (int)floorf((pj.x - tlx) * 4.0f);
        int cy = (int)floorf((tly - pj.y) * 4.0f);
        int g = cx + cy * 8;

        unsigned long long hitmask = __ballot(!oob);
        // distinct-cell mask (wave-uniform scalar loop over hits)
        unsigned long long m = hitmask, cellmask = 0ull;
        while (m) {
            int j = __builtin_ctzll(m); m &= m - 1;
            int gj = __shfl(g, j);
            cellmask |= 1ull << gj;
        }
        int n_nz = __popcll(cellmask);
        int base = 0;
        if (lane == 0) base = atomicAdd(counter, n_nz);
        base = __shfl(base, 0);
        if (lane == 0) { cntA[b] = n_nz; baseA[b] = base; }

        // h -> bf16 for this anchor's row
        h_bf[(size_t)b * 64 + lane] = f2bf(h[(size_t)b * 64 + lane]);

        // per distinct cell (ascending g): sum contributing peers, write row
        unsigned long long cm = cellmask;
        int slot = 0;
        while (cm) {
            int gg = __builtin_ctzll(cm); cm &= cm - 1;
            unsigned long long jm = __ballot((!oob) && (g == gg));
            float sum = 0.f;
            while (jm) {
                int j = __builtin_ctzll(jm); jm &= jm - 1;
                sum += hrow[j * H_DIM + lane];
            }
            enc[((size_t)(b * G + gg)) * H_DIM + lane] = f2bf(sum);
            if (lane == 0) rowidx[base + slot] = b * G + gg;
            ++slot;
        }
    } else if (blk < 528) {
        // ---- Wte[n][k] = bf16(W_enc[k][n]), 64x1024 -> 1024x64 ----
        int n0 = (blk - 512) * 64;
        #pragma unroll
        for (int idx = 0; idx < 16; ++idx) {
            int flat = t + 256 * idx;
            int k = flat >> 6, c = flat & 63;
            tileT[k][c] = W_enc[(size_t)k * ATT + n0 + c];
        }
        __syncthreads();
        #pragma unroll
        for (int idx = 0; idx < 16; ++idx) {
            int flat = t + 256 * idx;
            int n = flat >> 6, k = flat & 63;
            Wte[(size_t)(n0 + n) * 64 + k] = f2bf(tileT[k][n]);
        }
    } else if (blk < 544) {
        // ---- Wdt[n][k] = bf16(W_dec[k][n]) ----
        int n0 = (blk - 528) * 64;
        #pragma unroll
        for (int idx = 0; idx < 16; ++idx) {
            int flat = t + 256 * idx;
            int k = flat >> 6, c = flat & 63;
            tileT[k][c] = W_dec[(size_t)k * ATT + n0 + c];
        }
        __syncthreads();
        #pragma unroll
        for (int idx = 0; idx < 16; ++idx) {
            int flat = t + 256 * idx;
            int n = flat >> 6, k = flat & 63;
            Wdt[(size_t)(n0 + n) * 64 + k] = f2bf(tileT[k][n]);
        }
    } else if (blk < 560) {
        // ---- Wot[n][k] = bf16(W_out[k][n]) for k<68 else 0, layout 1024x96 ----
        int n0 = (blk - 544) * 64;
        int n = t & 63, kg = t >> 6;
        #pragma unroll
        for (int kk = 0; kk < 24; ++kk) {
            int k = kg * 24 + kk;
            float v = (k < 68) ? W_out[(size_t)k * ATT + n0 + n] : 0.f;
            Wot[(size_t)(n0 + n) * 96 + k] = f2bf(v);
        }
    } else {
        // ---- Wt[n][k] = bf16(W_mlp[k][n]), 1024x1024 in 64x64 tiles ----
        int idx2 = blk - 560;
        int k0 = (idx2 & 15) * 64, n0 = (idx2 >> 4) * 64;
        #pragma unroll
        for (int idx = 0; idx < 16; ++idx) {
            int flat = t + 256 * idx;
            int r = flat >> 6, c = flat & 63;
            tileT[r][c] = W_mlp[(size_t)(k0 + r) * ATT + n0 + c];
        }
        __syncthreads();
        #pragma unroll
        for (int idx = 0; idx < 16; ++idx) {
            int flat = t + 256 * idx;
            int r = flat >> 6, c = flat & 63;
            Wt[(size_t)(n0 + r) * ATT + k0 + c] = f2bf(tileT[c][r]);
        }
    }
}

// ---------------- K2: dec_r = h_bf @ Wdt^T + b_dec + b_enc (MFMA) ; s_empty += relu(v).w_full ----------------
__global__ __launch_bounds__(256) void dec_mfma_kernel(const ushort* __restrict__ A,   // h_bf [2048][64]
                                                       const ushort* __restrict__ Bt,  // Wdt [1024][64]
                                                       const float* __restrict__ b_dec,
                                                       const float* __restrict__ b_enc,
                                                       const float* __restrict__ w_full,
                                                       float* __restrict__ dec_r,
                                                       float* __restrict__ s_empty) {
    int t = threadIdx.x;
    int w = t >> 6, lane = t & 63;
    int lm = lane & 15, q = lane >> 4;
    int m0 = blockIdx.x * 64, n1 = blockIdx.y * 128;
    __shared__ __align__(16) ushort Asm[64][72];
    __shared__ __align__(16) ushort Bsm[128][72];

    #pragma unroll
    for (int i = 0; i < 4; ++i) {
        int flat = t + 256 * i;
        int r = flat >> 4, c4 = (flat & 15) * 4;
        *(uint2*)&Asm[r][c4] = *(const uint2*)&A[(size_t)(m0 + r) * 64 + c4];
    }
    #pragma unroll
    for (int i = 0; i < 8; ++i) {
        int flat = t + 256 * i;
        int r = flat >> 4, c4 = (flat & 15) * 4;
        *(uint2*)&Bsm[r][c4] = *(const uint2*)&Bt[(size_t)(n1 + r) * 64 + c4];
    }
    __syncthreads();

    floatx4 acc[4][2];
    #pragma unroll
    for (int mt = 0; mt < 4; ++mt)
        #pragma unroll
        for (int nt = 0; nt < 2; ++nt) acc[mt][nt] = (floatx4){0.f, 0.f, 0.f, 0.f};

    #pragma unroll
    for (int ks = 0; ks < 64; ks += 32) {
        short8 af[4], bfr[2];
        #pragma unroll
        for (int mt = 0; mt < 4; ++mt)
            af[mt] = *(const short8*)&Asm[mt * 16 + lm][ks + q * 8];
        #pragma unroll
        for (int nt = 0; nt < 2; ++nt)
            bfr[nt] = *(const short8*)&Bsm[w * 32 + nt * 16 + lm][ks + q * 8];
        #pragma unroll
        for (int mt = 0; mt < 4; ++mt)
            #pragma unroll
            for (int nt = 0; nt < 2; ++nt)
                acc[mt][nt] = __builtin_amdgcn_mfma_f32_16x16x32_bf16(af[mt], bfr[nt], acc[mt][nt], 0, 0, 0);
    }

    float part[4][4];
    #pragma unroll
    for (int mt = 0; mt < 4; ++mt)
        #pragma unroll
        for (int r = 0; r < 4; ++r) part[mt][r] = 0.f;

    #pragma unroll
    for (int nt = 0; nt < 2; ++nt) {
        int col = n1 + w * 32 + nt * 16 + lm;
        float bcol = b_dec[col] + b_enc[col];
        float wf = w_full[col];
        #pragma unroll
        for (int mt = 0; mt < 4; ++mt)
            #pragma unroll
            for (int r = 0; r < 4; ++r) {
                int row = m0 + mt * 16 + q * 4 + r;
                float v = acc[mt][nt][r] + bcol;
                dec_r[(size_t)row * ATT + col] = v;
                part[mt][r] += fmaxf(v, 0.f) * wf;
            }
    }
    #pragma unroll
    for (int mt = 0; mt < 4; ++mt)
        #pragma unroll
        for (int r = 0; r < 4; ++r) {
            float v = part[mt][r];
            v += __shfl_xor(v, 1); v += __shfl_xor(v, 2);
            v += __shfl_xor(v, 4); v += __shfl_xor(v, 8);
            part[mt][r] = v;
        }
    if (lm == 0) {
        #pragma unroll
        for (int mt = 0; mt < 4; ++mt)
            #pragma unroll
            for (int r = 0; r < 4; ++r)
                atomicAdd(&s_empty[m0 + mt * 16 + q * 4 + r], part[mt][r]);
    }
}

// ---------------- K3: scores over compact rows (MFMA bf16) ----------------
__global__ __launch_bounds__(256) void scoresC_mfma_kernel(const ushort* __restrict__ enc,
                                                           const int* __restrict__ rowidx,
                                                           const int* __restrict__ counter,
                                                           const float* __restrict__ dec_r,
                                                           const ushort* __restrict__ Wte,
                                                           const float* __restrict__ w_full,
                                                           const float* __restrict__ b_full,
                                                           float* __restrict__ score_c) {
    int M = counter[0];
    int row0 = blockIdx.x * 64;
    if (row0 >= M) return;
    int t = threadIdx.x;
    int w = t >> 6, lane = t & 63;
    int lm = lane & 15, q = lane >> 4;

    __shared__ __align__(16) ushort AS[64][72];    // enc rows [m][k]
    __shared__ __align__(16) ushort BS[256][72];   // W_enc^T chunk [n][k]
    __shared__ int rowS[64];
    __shared__ float redS[4][64];

    if (t < 64) rowS[t] = (row0 + t < M) ? rowidx[row0 + t] : 0;
    __syncthreads();
    #pragma unroll
    for (int i = 0; i < 4; ++i) {
        int flat = t + 256 * i;
        int r = flat >> 4, c4 = (flat & 15) * 4;
        *(uint2*)&AS[r][c4] = *(const uint2*)&enc[(size_t)rowS[r] * 64 + c4];
    }
    int bbr[16];
    #pragma unroll
    for (int mt = 0; mt < 4; ++mt)
        #pragma unroll
        for (int r = 0; r < 4; ++r)
            bbr[mt * 4 + r] = rowS[mt * 16 + q * 4 + r] >> 6;

    float part[4][4];
    #pragma unroll
    for (int mt = 0; mt < 4; ++mt)
        #pragma unroll
        for (int r = 0; r < 4; ++r) part[mt][r] = 0.f;

    for (int c = 0; c < 4; ++c) {
        __syncthreads();
        #pragma unroll
        for (int i = 0; i < 16; ++i) {
            int flat = t + 256 * i;
            int r = flat >> 4, c4 = (flat & 15) * 4;
            *(uint2*)&BS[r][c4] = *(const uint2*)&Wte[(size_t)(c * 256 + r) * 64 + c4];
        }
        __syncthreads();

        floatx4 acc[4][4];
        #pragma unroll
        for (int mt = 0; mt < 4; ++mt)
            #pragma unroll
            for (int nt = 0; nt < 4; ++nt) acc[mt][nt] = (floatx4){0.f, 0.f, 0.f, 0.f};

        #pragma unroll
        for (int ks = 0; ks < 64; ks += 32) {
            short8 af[4], bfr[4];
            #pragma unroll
            for (int mt = 0; mt < 4; ++mt)
                af[mt] = *(const short8*)&AS[mt * 16 + lm][ks + q * 8];
            #pragma unroll
            for (int nt = 0; nt < 4; ++nt)
                bfr[nt] = *(const short8*)&BS[w * 64 + nt * 16 + lm][ks + q * 8];
            #pragma unroll
            for (int mt = 0; mt < 4; ++mt)
                #pragma unroll
                for (int nt = 0; nt < 4; ++nt)
                    acc[mt][nt] = __builtin_amdgcn_mfma_f32_16x16x32_bf16(af[mt], bfr[nt], acc[mt][nt], 0, 0, 0);
        }

        int colbase = c * 256 + w * 64;
        #pragma unroll
        for (int nt = 0; nt < 4; ++nt) {
            int col = colbase + nt * 16 + lm;
            float wf = w_full[col];
            #pragma unroll
            for (int mt = 0; mt < 4; ++mt)
                #pragma unroll
                for (int r = 0; r < 4; ++r) {
                    float v = acc[mt][nt][r] + dec_r[(size_t)bbr[mt * 4 + r] * ATT + col];
                    part[mt][r] += fmaxf(v, 0.f) * wf;
                }
        }
    }
    #pragma unroll
    for (int mt = 0; mt < 4; ++mt)
        #pragma unroll
        for (int r = 0; r < 4; ++r) {
            float v = part[mt][r];
            v += __shfl_xor(v, 1); v += __shfl_xor(v, 2);
            v += __shfl_xor(v, 4); v += __shfl_xor(v, 8);
            part[mt][r] = v;
        }
    if (lm == 0) {
        #pragma unroll
        for (int mt = 0; mt < 4; ++mt)
            #pragma unroll
            for (int r = 0; r < 4; ++r)
                redS[w][mt * 16 + q * 4 + r] = part[mt][r];
    }
    __syncthreads();
    if (t < 64) {
        int row = row0 + t;
        if (row < M)
            score_c[row] = redS[0][t] + redS[1][t] + redS[2][t] + redS[3][t] + b_full[0];
    }
}

// ---------------- K4: softmax + ctx + emb -> ctx_bf[2048][96] (bf16, zero-padded) ----------------
__global__ __launch_bounds__(64) void softmax_ctx_kernel(const float* __restrict__ score_c,
                                                         const int* __restrict__ rowidx,
                                                         const int* __restrict__ cntA,
                                                         const int* __restrict__ baseA,
                                                         const float* __restrict__ s_empty,
                                                         const ushort* __restrict__ enc,
                                                         const float* __restrict__ end_pos,
                                                         const float* __restrict__ rel_pos,
                                                         const float* __restrict__ W_embed,
                                                         const float* __restrict__ b_embed,
                                                         const float* __restrict__ b_full,
                                                         ushort* __restrict__ ctx_bf) {
    int b = blockIdx.x, t = threadIdx.x;
    int cnt = cntA[b], base = baseA[b];
    float se = s_empty[b] + b_full[0];
    float sc = se;
    int ri = 0;
    if (t < cnt) { sc = score_c[base + t]; ri = rowidx[base + t]; }
    float mx = sc;
    #pragma unroll
    for (int o = 32; o > 0; o >>= 1) mx = fmaxf(mx, __shfl_xor(mx, o));
    float e = expf(sc - mx);
    float ssum = e;
    #pragma unroll
    for (int o = 32; o > 0; o >>= 1) ssum += __shfl_xor(ssum, o);
    __shared__ float aS[G];
    __shared__ int rS[G];
    aS[t] = e / ssum;
    rS[t] = ri;
    __syncthreads();
    float ctx = 0.f;
    for (int i = 0; i < cnt; ++i)
        ctx += aS[i] * bf2f(enc[(size_t)rS[i] * H_DIM + t]);
    ctx_bf[(size_t)b * 96 + t] = f2bf(ctx);
    if (t < EMB) {
        float e0 = end_pos[2*b], e1 = end_pos[2*b+1], e2 = rel_pos[2*b], e3 = rel_pos[2*b+1];
        float v = b_embed[t] + e0 * W_embed[0*EMB + t] + e1 * W_embed[1*EMB + t]
                             + e2 * W_embed[2*EMB + t] + e3 * W_embed[3*EMB + t];
        ctx_bf[(size_t)b * 96 + 64 + t] = f2bf(v > 0.f ? v : 0.f);
    }
    if (t < 28) ctx_bf[(size_t)b * 96 + 68 + t] = 0;
}

// ---------------- K5: out_bf = bf16(relu(ctx_bf @ Wot^T + b_out))  (MFMA, K=96) ----------------
__global__ __launch_bounds__(256) void out_mfma_kernel(const ushort* __restrict__ A,   // ctx_bf [2048][96]
                                                       const ushort* __restrict__ Bt,  // Wot [1024][96]
                                                       const float* __restrict__ bias,
                                                       ushort* __restrict__ out) {
    int t = threadIdx.x;
    int w = t >> 6, lane = t & 63;
    int lm = lane & 15, q = lane >> 4;
    int m0 = blockIdx.x * 64, n1 = blockIdx.y * 128;
    __shared__ __align__(16) ushort Asm[64][104];
    __shared__ __align__(16) ushort Bsm[128][104];

    {   // A: 64 rows x 96 ush = 12 uint4/row; 4 threads/row x 3 each
        int r = t >> 2, pp = t & 3;
        #pragma unroll
        for (int ii = 0; ii < 3; ++ii) {
            int c8 = (pp * 3 + ii) * 8;
            *(uint4*)&Asm[r][c8] = *(const uint4*)&A[(size_t)(m0 + r) * 96 + c8];
        }
    }
    {   // B: 128 rows x 96 ush; 2 threads/row x 6 each
        int r = t >> 1, pp = t & 1;
        #pragma unroll
        for (int ii = 0; ii < 6; ++ii) {
            int c8 = (pp * 6 + ii) * 8;
            *(uint4*)&Bsm[r][c8] = *(const uint4*)&Bt[(size_t)(n1 + r) * 96 + c8];
        }
    }
    __syncthreads();

    floatx4 acc[4][2];
    #pragma unroll
    for (int mt = 0; mt < 4; ++mt)
        #pragma unroll
        for (int nt = 0; nt < 2; ++nt) acc[mt][nt] = (floatx4){0.f, 0.f, 0.f, 0.f};

    #pragma unroll
    for (int ks = 0; ks < 96; ks += 32) {
        short8 af[4], bfr[2];
        #pragma unroll
        for (int mt = 0; mt < 4; ++mt)
            af[mt] = *(const short8*)&Asm[mt * 16 + lm][ks + q * 8];
        #pragma unroll
        for (int nt = 0; nt < 2; ++nt)
            bfr[nt] = *(const short8*)&Bsm[w * 32 + nt * 16 + lm][ks + q * 8];
        #pragma unroll
        for (int mt = 0; mt < 4; ++mt)
            #pragma unroll
            for (int nt = 0; nt < 2; ++nt)
                acc[mt][nt] = __builtin_amdgcn_mfma_f32_16x16x32_bf16(af[mt], bfr[nt], acc[mt][nt], 0, 0, 0);
    }
    #pragma unroll
    for (int nt = 0; nt < 2; ++nt) {
        int col = n1 + w * 32 + nt * 16 + lm;
        float bv = bias[col];
        #pragma unroll
        for (int mt = 0; mt < 4; ++mt)
            #pragma unroll
            for (int r = 0; r < 4; ++r) {
                int row = m0 + mt * 16 + q * 4 + r;
                out[(size_t)row * ATT + col] = f2bf(fmaxf(acc[mt][nt][r] + bv, 0.f));
            }
    }
}

// ---------------- K6: x = out_bf @ Wt^T + b_mlp (MFMA) + fused BN stats ----------------
__global__ __launch_bounds__(256) void mlp_mfma_kernel(const ushort* __restrict__ A,   // [2048][1024] bf16
                                                       const ushort* __restrict__ Bt,  // [1024][1024] bf16
                                                       const float* __restrict__ bias,
                                                       float* __restrict__ X,
                                                       float* __restrict__ sums) {
    int t = threadIdx.x;
    int w = t >> 6, lane = t & 63;
    int lm = lane & 15, q = lane >> 4;
    int m0 = blockIdx.x * 64, n1 = blockIdx.y * 128;
    __shared__ __align__(16) ushort Asm[64][72];
    __shared__ __align__(16) ushort Bsm[128][72];

    floatx4 acc[4][2];
    #pragma unroll
    for (int mt = 0; mt < 4; ++mt)
        #pragma unroll
        for (int nt = 0; nt < 2; ++nt) acc[mt][nt] = (floatx4){0.f, 0.f, 0.f, 0.f};

    for (int k0 = 0; k0 < 1024; k0 += 64) {
        __syncthreads();
        #pragma unroll
        for (int i = 0; i < 4; ++i) {
            int flat = t + 256 * i;
            int r = flat >> 4, c4 = (flat & 15) * 4;
            *(uint2*)&Asm[r][c4] = *(const uint2*)&A[(size_t)(m0 + r) * 1024 + k0 + c4];
        }
        #pragma unroll
        for (int i = 0; i < 8; ++i) {
            int flat = t + 256 * i;
            int r = flat >> 4, c4 = (flat & 15) * 4;
            *(uint2*)&Bsm[r][c4] = *(const uint2*)&Bt[(size_t)(n1 + r) * 1024 + k0 + c4];
        }
        __syncthreads();
        #pragma unroll
        for (int ks = 0; ks < 64; ks += 32) {
            short8 af[4], bfr[2];
            #pragma unroll
            for (int mt = 0; mt < 4; ++mt)
                af[mt] = *(const short8*)&Asm[mt * 16 + lm][ks + q * 8];
            #pragma unroll
            for (int nt = 0; nt < 2; ++nt)
                bfr[nt] = *(const short8*)&Bsm[w * 32 + nt * 16 + lm][ks + q * 8];
            #pragma unroll
            for (int mt = 0; mt < 4; ++mt)
                #pragma unroll
                for (int nt = 0; nt < 2; ++nt)
                    acc[mt][nt] = __builtin_amdgcn_mfma_f32_16x16x32_bf16(af[mt], bfr[nt], acc[mt][nt], 0, 0, 0);
        }
    }
    #pragma unroll
    for (int nt = 0; nt < 2; ++nt) {
        int col = n1 + w * 32 + nt * 16 + lm;
        float bv = bias[col];
        float s1 = 0.f, s2 = 0.f;
        #pragma unroll
        for (int mt = 0; mt < 4; ++mt)
            #pragma unroll
            for (int r = 0; r < 4; ++r) {
                int row = m0 + mt * 16 + q * 4 + r;
                float v = acc[mt][nt][r] + bv;
                X[(size_t)row * 1024 + col] = v;
                s1 += v; s2 += v * v;
            }
        s1 += __shfl_xor(s1, 16); s1 += __shfl_xor(s1, 32);
        s2 += __shfl_xor(s2, 16); s2 += __shfl_xor(s2, 32);
        if (q == 0) {
            atomicAdd(&sums[col], s1);
            atomicAdd(&sums[ATT + col], s2);
        }
    }
}

// ---------------- K7: normalize + relu -> d_out ----------------
__global__ __launch_bounds__(256) void bn_kernel(const float* __restrict__ X,
                                                 const float* __restrict__ sums,
                                                 const float* __restrict__ gamma,
                                                 const float* __restrict__ beta,
                                                 float* __restrict__ out) {
    size_t i = (size_t)blockIdx.x * 256 + threadIdx.x;
    int f = (int)(i & 1023);
    float mu = sums[f] * (1.f / BB);
    float var = sums[ATT + f] * (1.f / BB) - mu * mu;
    float v = (X[i] - mu) * rsqrtf(var + 1e-5f) * gamma[f] + beta[f];
    out[i] = v > 0.f ? v : 0.f;
}

extern "C" void kernel_launch(void* const* d_in, const int* in_sizes, int n_in,
                              void* d_out, int out_size, void* d_ws, size_t ws_size,
                              hipStream_t stream) {
    const float* h        = (const float*)d_in[0];
    const float* end_pos  = (const float*)d_in[2];
    const float* rel_pos  = (const float*)d_in[3];
    const float* W_enc    = (const float*)d_in[4];
    const float* b_enc    = (const float*)d_in[5];
    const float* W_dec    = (const float*)d_in[6];
    const float* b_dec    = (const float*)d_in[7];
    const float* w_full   = (const float*)d_in[8];
    const float* b_full   = (const float*)d_in[9];
    const float* W_embed  = (const float*)d_in[10];
    const float* b_embed  = (const float*)d_in[11];
    const float* W_out    = (const float*)d_in[12];
    const float* b_out    = (const float*)d_in[13];
    const float* W_mlp    = (const float*)d_in[14];
    const float* b_mlp    = (const float*)d_in[15];
    const float* bn_gamma = (const float*)d_in[16];
    const float* bn_beta  = (const float*)d_in[17];

    float* ws = (float*)d_ws;
    // Layout (float-unit offsets), no aliasing:
    ushort* enc     = (ushort*)ws;                 // 131072 x 64 bf16  -> [0, 4,194,304)
    ushort* h_bf    = (ushort*)(ws + 4194304);     // 2048 x 64 bf16    (65,536 fl)
    ushort* Wte     = (ushort*)(ws + 4259840);     // 1024 x 64 bf16    (32,768 fl)
    ushort* Wdt     = (ushort*)(ws + 4292608);     // 1024 x 64 bf16    (32,768 fl)
    ushort* Wot     = (ushort*)(ws + 4325376);     // 1024 x 96 bf16    (49,152 fl)
    ushort* Wt      = (ushort*)(ws + 4374528);     // 1024 x 1024 bf16  (524,288 fl)
    ushort* ctx_bf  = (ushort*)(ws + 4898816);     // 2048 x 96 bf16    (98,304 fl)
    ushort* out_bf  = (ushort*)(ws + 4997120);     // 2048 x 1024 bf16  (1,048,576 fl)
    float*  x       = ws + 6045696;                // 2048 x 1024 fp32  (2,097,152 fl)
    float*  dec_r   = ws + 8388608;                // 2048 x 1024 fp32  (2,097,152 fl)
    int*    rowidx  = (int*)(ws + 10485760);       // 131,072
    float*  score_c = ws + 10616832;               // 131,072
    int*    cntA    = (int*)(ws + 10747904);       // 2,048
    int*    baseA   = (int*)(ws + 10749952);       // 2,048
    // zero block: counter(64) + s_empty(2048) + sums(2048)
    int*    counter = (int*)(ws + 10752000);
    float*  s_empty = ws + 10752064;
    float*  sums    = ws + 10754112;

    hipMemsetAsync(counter, 0, (64 + 2048 + 2048) * sizeof(float), stream);

    prep_kernel<<<PREP_BLOCKS, 256, 0, stream>>>(h, end_pos, W_enc, W_dec, W_out, W_mlp,
                                                 enc, h_bf, Wte, Wdt, Wot, Wt,
                                                 rowidx, cntA, baseA, counter);
    dec_mfma_kernel<<<dim3(32, 8), 256, 0, stream>>>(h_bf, Wdt, b_dec, b_enc, w_full, dec_r, s_empty);
    scoresC_mfma_kernel<<<MAXROWS / 64, 256, 0, stream>>>(enc, rowidx, counter, dec_r, Wte,
                                                          w_full, b_full, score_c);
    softmax_ctx_kernel<<<BB, 64, 0, stream>>>(score_c, rowidx, cntA, baseA, s_empty, enc,
                                              end_pos, rel_pos, W_embed, b_embed, b_full, ctx_bf);
    out_mfma_kernel<<<dim3(32, 8), 256, 0, stream>>>(ctx_bf, Wot, b_out, out_bf);
    mlp_mfma_kernel<<<dim3(32, 8), 256, 0, stream>>>(out_bf, Wt, b_mlp, x, sums);
    bn_kernel<<<8192, 256, 0, stream>>>(x, sums, bn_gamma, bn_beta, (float*)d_out);
}

// Round 7
// 167.156 us; speedup vs baseline: 3.1832x; 1.1710x over previous
//
#include <hip/hip_runtime.h>
#include <hip/hip_bf16.h>
#include <math.h>

#define H_DIM 64
#define G 64
#define ATT 1024
#define EMB 4
#define P 64
#define BB 2048   // batch B = S*P
#define MAXROWS 129088  // 2048*63 rounded up to multiple of 64
#define PREP_BLOCKS 817
#define MAGICF 0x13579BDF

typedef __attribute__((ext_vector_type(8))) short short8;
typedef __attribute__((ext_vector_type(4))) float floatx4;

__device__ inline ushort f2bf(float v) {
    __hip_bfloat16 b = __float2bfloat16(v);
    return *(ushort*)&b;
}
__device__ inline float bf2f(ushort u) {
    union { float f; unsigned u32; } x;
    x.u32 = ((unsigned)u) << 16;
    return x.f;
}

// ---------------- K1: prep = init | pool | W_enc^T | W_dec^T | W_out^T(pad96) | W_mlp^T ----------------
// block 0: zero counter+sums (device-scope), publish MAGIC flag.
// blocks 1..512: pool, one wave per anchor, ballot-based; ONE atomicAdd per block (4 anchors).
__global__ __launch_bounds__(256) void prep_kernel(const float* __restrict__ h,
                                                   const float* __restrict__ end_pos,
                                                   const float* __restrict__ W_enc,
                                                   const float* __restrict__ W_dec,
                                                   const float* __restrict__ W_out,
                                                   const float* __restrict__ W_mlp,
                                                   ushort* __restrict__ enc,
                                                   ushort* __restrict__ h_bf,
                                                   ushort* __restrict__ Wte,
                                                   ushort* __restrict__ Wdt,
                                                   ushort* __restrict__ Wot,
                                                   ushort* __restrict__ Wt,
                                                   int* __restrict__ rowidx,
                                                   int* __restrict__ cntA,
                                                   int* __restrict__ baseA,
                                                   int* __restrict__ counter,
                                                   float* __restrict__ sums,
                                                   int* __restrict__ flag) {
    __shared__ float tileT[64][65];        // transpose branches only (16.25 KB)
    __shared__ int nzS[4], baseSh[4];

    int blk = blockIdx.x;
    int t = threadIdx.x;

    if (blk == 0) {
        // ---- init: device-scope zeroing visible to coherent point, then publish ----
        if (t < 64) __hip_atomic_store(&counter[t], 0, __ATOMIC_RELAXED, __HIP_MEMORY_SCOPE_AGENT);
        int* sz = (int*)sums;
        for (int i = t; i < 2048; i += 256)
            __hip_atomic_store(&sz[i], 0, __ATOMIC_RELAXED, __HIP_MEMORY_SCOPE_AGENT);
        __syncthreads();
        if (t == 0) __hip_atomic_store(flag, MAGICF, __ATOMIC_RELEASE, __HIP_MEMORY_SCOPE_AGENT);
    } else if (blk <= 512) {
        // ---- social pooling: wave wv handles anchor b = (blk-1)*4+wv ----
        int wv = t >> 6, lane = t & 63;
        int b = (blk - 1) * 4 + wv;
        int s = b >> 6, i = b & 63;
        const float* pseq = end_pos + (size_t)s * P * 2;
        const float* hrow = h + (size_t)s * P * H_DIM;

        float2 pj = ((const float2*)pseq)[lane];
        float ax = __shfl(pj.x, i), ay = __shfl(pj.y, i);
        float tlx = ax - 1.f, tly = ay + 1.f, brx = ax + 1.f, bry = ay - 1.f;
        bool oob = (pj.x >= brx) || (pj.x <= tlx) || (pj.y >= tly) || (pj.y <= bry) || (lane == i);
        int cx = (int)floorf((pj.x - tlx) * 4.0f);
        int cy = (int)floorf((tly - pj.y) * 4.0f);
        int g = cx + cy * 8;

        unsigned long long hitmask = __ballot(!oob);
        unsigned long long m = hitmask, cellmask = 0ull;
        while (m) {
            int j = __builtin_ctzll(m); m &= m - 1;
            int gj = __shfl(g, j);
            cellmask |= 1ull << gj;
        }
        int n_nz = __popcll(cellmask);
        if (lane == 0) nzS[wv] = n_nz;

        // h -> bf16 for this anchor's row (overlaps the spin below)
        h_bf[(size_t)b * 64 + lane] = f2bf(h[(size_t)b * 64 + lane]);

        __syncthreads();
        if (t == 0) {
            while (__hip_atomic_load(flag, __ATOMIC_ACQUIRE, __HIP_MEMORY_SCOPE_AGENT) != MAGICF) {}
            int n0 = nzS[0], n1 = nzS[1], n2 = nzS[2], n3 = nzS[3];
            int base = atomicAdd(counter, n0 + n1 + n2 + n3);
            baseSh[0] = base;
            baseSh[1] = base + n0;
            baseSh[2] = base + n0 + n1;
            baseSh[3] = base + n0 + n1 + n2;
        }
        __syncthreads();
        int base = baseSh[wv];
        if (lane == 0) { cntA[b] = n_nz; baseA[b] = base; }

        unsigned long long cm = cellmask;
        int slot = 0;
        while (cm) {
            int gg = __builtin_ctzll(cm); cm &= cm - 1;
            unsigned long long jm = __ballot((!oob) && (g == gg));
            float sum = 0.f;
            while (jm) {
                int j = __builtin_ctzll(jm); jm &= jm - 1;
                sum += hrow[j * H_DIM + lane];
            }
            enc[((size_t)(b * G + gg)) * H_DIM + lane] = f2bf(sum);
            if (lane == 0) rowidx[base + slot] = b * G + gg;
            ++slot;
        }
    } else if (blk <= 528) {
        // ---- Wte[n][k] = bf16(W_enc[k][n]) ----
        int n0 = (blk - 513) * 64;
        #pragma unroll
        for (int idx = 0; idx < 16; ++idx) {
            int flat = t + 256 * idx;
            int k = flat >> 6, c = flat & 63;
            tileT[k][c] = W_enc[(size_t)k * ATT + n0 + c];
        }
        __syncthreads();
        #pragma unroll
        for (int idx = 0; idx < 16; ++idx) {
            int flat = t + 256 * idx;
            int n = flat >> 6, k = flat & 63;
            Wte[(size_t)(n0 + n) * 64 + k] = f2bf(tileT[k][n]);
        }
    } else if (blk <= 544) {
        // ---- Wdt[n][k] = bf16(W_dec[k][n]) ----
        int n0 = (blk - 529) * 64;
        #pragma unroll
        for (int idx = 0; idx < 16; ++idx) {
            int flat = t + 256 * idx;
            int k = flat >> 6, c = flat & 63;
            tileT[k][c] = W_dec[(size_t)k * ATT + n0 + c];
        }
        __syncthreads();
        #pragma unroll
        for (int idx = 0; idx < 16; ++idx) {
            int flat = t + 256 * idx;
            int n = flat >> 6, k = flat & 63;
            Wdt[(size_t)(n0 + n) * 64 + k] = f2bf(tileT[k][n]);
        }
    } else if (blk <= 560) {
        // ---- Wot[n][k] = bf16(W_out[k][n]) for k<68 else 0, layout 1024x96 ----
        int n0 = (blk - 545) * 64;
        int n = t & 63, kg = t >> 6;
        #pragma unroll
        for (int kk = 0; kk < 24; ++kk) {
            int k = kg * 24 + kk;
            float v = (k < 68) ? W_out[(size_t)k * ATT + n0 + n] : 0.f;
            Wot[(size_t)(n0 + n) * 96 + k] = f2bf(v);
        }
    } else {
        // ---- Wt[n][k] = bf16(W_mlp[k][n]), 1024x1024 in 64x64 tiles ----
        int idx2 = blk - 561;
        int k0 = (idx2 & 15) * 64, n0 = (idx2 >> 4) * 64;
        #pragma unroll
        for (int idx = 0; idx < 16; ++idx) {
            int flat = t + 256 * idx;
            int r = flat >> 6, c = flat & 63;
            tileT[r][c] = W_mlp[(size_t)(k0 + r) * ATT + n0 + c];
        }
        __syncthreads();
        #pragma unroll
        for (int idx = 0; idx < 16; ++idx) {
            int flat = t + 256 * idx;
            int r = flat >> 6, c = flat & 63;
            Wt[(size_t)(n0 + r) * ATT + k0 + c] = f2bf(tileT[c][r]);
        }
    }
}

// ---------------- K2: dec_r = h_bf @ Wdt^T + b_dec + b_enc (MFMA); s_part[32][2048] partials ----------------
__global__ __launch_bounds__(256) void dec_mfma_kernel(const ushort* __restrict__ A,   // h_bf [2048][64]
                                                       const ushort* __restrict__ Bt,  // Wdt [1024][64]
                                                       const float* __restrict__ b_dec,
                                                       const float* __restrict__ b_enc,
                                                       const float* __restrict__ w_full,
                                                       float* __restrict__ dec_r,
                                                       float* __restrict__ s_part) {
    int t = threadIdx.x;
    int w = t >> 6, lane = t & 63;
    int lm = lane & 15, q = lane >> 4;
    int m0 = blockIdx.x * 64, n1 = blockIdx.y * 128;
    __shared__ __align__(16) ushort Asm[64][72];
    __shared__ __align__(16) ushort Bsm[128][72];

    #pragma unroll
    for (int i = 0; i < 4; ++i) {
        int flat = t + 256 * i;
        int r = flat >> 4, c4 = (flat & 15) * 4;
        *(uint2*)&Asm[r][c4] = *(const uint2*)&A[(size_t)(m0 + r) * 64 + c4];
    }
    #pragma unroll
    for (int i = 0; i < 8; ++i) {
        int flat = t + 256 * i;
        int r = flat >> 4, c4 = (flat & 15) * 4;
        *(uint2*)&Bsm[r][c4] = *(const uint2*)&Bt[(size_t)(n1 + r) * 64 + c4];
    }
    __syncthreads();

    floatx4 acc[4][2];
    #pragma unroll
    for (int mt = 0; mt < 4; ++mt)
        #pragma unroll
        for (int nt = 0; nt < 2; ++nt) acc[mt][nt] = (floatx4){0.f, 0.f, 0.f, 0.f};

    #pragma unroll
    for (int ks = 0; ks < 64; ks += 32) {
        short8 af[4], bfr[2];
        #pragma unroll
        for (int mt = 0; mt < 4; ++mt)
            af[mt] = *(const short8*)&Asm[mt * 16 + lm][ks + q * 8];
        #pragma unroll
        for (int nt = 0; nt < 2; ++nt)
            bfr[nt] = *(const short8*)&Bsm[w * 32 + nt * 16 + lm][ks + q * 8];
        #pragma unroll
        for (int mt = 0; mt < 4; ++mt)
            #pragma unroll
            for (int nt = 0; nt < 2; ++nt)
                acc[mt][nt] = __builtin_amdgcn_mfma_f32_16x16x32_bf16(af[mt], bfr[nt], acc[mt][nt], 0, 0, 0);
    }

    float part[4][4];
    #pragma unroll
    for (int mt = 0; mt < 4; ++mt)
        #pragma unroll
        for (int r = 0; r < 4; ++r) part[mt][r] = 0.f;

    #pragma unroll
    for (int nt = 0; nt < 2; ++nt) {
        int col = n1 + w * 32 + nt * 16 + lm;
        float bcol = b_dec[col] + b_enc[col];
        float wf = w_full[col];
        #pragma unroll
        for (int mt = 0; mt < 4; ++mt)
            #pragma unroll
            for (int r = 0; r < 4; ++r) {
                int row = m0 + mt * 16 + q * 4 + r;
                float v = acc[mt][nt][r] + bcol;
                dec_r[(size_t)row * ATT + col] = v;
                part[mt][r] += fmaxf(v, 0.f) * wf;
            }
    }
    #pragma unroll
    for (int mt = 0; mt < 4; ++mt)
        #pragma unroll
        for (int r = 0; r < 4; ++r) {
            float v = part[mt][r];
            v += __shfl_xor(v, 1); v += __shfl_xor(v, 2);
            v += __shfl_xor(v, 4); v += __shfl_xor(v, 8);
            part[mt][r] = v;
        }
    if (lm == 0) {
        int sp = blockIdx.y * 4 + w;   // 0..31
        #pragma unroll
        for (int mt = 0; mt < 4; ++mt)
            #pragma unroll
            for (int r = 0; r < 4; ++r)
                s_part[(size_t)sp * 2048 + m0 + mt * 16 + q * 4 + r] = part[mt][r];
    }
}

// ---------------- K3: scores over compact rows (MFMA bf16) ----------------
__global__ __launch_bounds__(256) void scoresC_mfma_kernel(const ushort* __restrict__ enc,
                                                           const int* __restrict__ rowidx,
                                                           const int* __restrict__ counter,
                                                           const float* __restrict__ dec_r,
                                                           const ushort* __restrict__ Wte,
                                                           const float* __restrict__ w_full,
                                                           const float* __restrict__ b_full,
                                                           float* __restrict__ score_c) {
    int M = counter[0];
    int row0 = blockIdx.x * 64;
    if (row0 >= M) return;
    int t = threadIdx.x;
    int w = t >> 6, lane = t & 63;
    int lm = lane & 15, q = lane >> 4;

    __shared__ __align__(16) ushort AS[64][72];    // enc rows [m][k]
    __shared__ __align__(16) ushort BS[256][72];   // W_enc^T chunk [n][k]
    __shared__ int rowS[64];
    __shared__ float redS[4][64];

    if (t < 64) rowS[t] = (row0 + t < M) ? rowidx[row0 + t] : 0;
    __syncthreads();
    #pragma unroll
    for (int i = 0; i < 4; ++i) {
        int flat = t + 256 * i;
        int r = flat >> 4, c4 = (flat & 15) * 4;
        *(uint2*)&AS[r][c4] = *(const uint2*)&enc[(size_t)rowS[r] * 64 + c4];
    }
    int bbr[16];
    #pragma unroll
    for (int mt = 0; mt < 4; ++mt)
        #pragma unroll
        for (int r = 0; r < 4; ++r)
            bbr[mt * 4 + r] = rowS[mt * 16 + q * 4 + r] >> 6;

    float part[4][4];
    #pragma unroll
    for (int mt = 0; mt < 4; ++mt)
        #pragma unroll
        for (int r = 0; r < 4; ++r) part[mt][r] = 0.f;

    for (int c = 0; c < 4; ++c) {
        __syncthreads();
        #pragma unroll
        for (int i = 0; i < 16; ++i) {
            int flat = t + 256 * i;
            int r = flat >> 4, c4 = (flat & 15) * 4;
            *(uint2*)&BS[r][c4] = *(const uint2*)&Wte[(size_t)(c * 256 + r) * 64 + c4];
        }
        __syncthreads();

        floatx4 acc[4][4];
        #pragma unroll
        for (int mt = 0; mt < 4; ++mt)
            #pragma unroll
            for (int nt = 0; nt < 4; ++nt) acc[mt][nt] = (floatx4){0.f, 0.f, 0.f, 0.f};

        #pragma unroll
        for (int ks = 0; ks < 64; ks += 32) {
            short8 af[4], bfr[4];
            #pragma unroll
            for (int mt = 0; mt < 4; ++mt)
                af[mt] = *(const short8*)&AS[mt * 16 + lm][ks + q * 8];
            #pragma unroll
            for (int nt = 0; nt < 4; ++nt)
                bfr[nt] = *(const short8*)&BS[w * 64 + nt * 16 + lm][ks + q * 8];
            #pragma unroll
            for (int mt = 0; mt < 4; ++mt)
                #pragma unroll
                for (int nt = 0; nt < 4; ++nt)
                    acc[mt][nt] = __builtin_amdgcn_mfma_f32_16x16x32_bf16(af[mt], bfr[nt], acc[mt][nt], 0, 0, 0);
        }

        int colbase = c * 256 + w * 64;
        #pragma unroll
        for (int nt = 0; nt < 4; ++nt) {
            int col = colbase + nt * 16 + lm;
            float wf = w_full[col];
            #pragma unroll
            for (int mt = 0; mt < 4; ++mt)
                #pragma unroll
                for (int r = 0; r < 4; ++r) {
                    float v = acc[mt][nt][r] + dec_r[(size_t)bbr[mt * 4 + r] * ATT + col];
                    part[mt][r] += fmaxf(v, 0.f) * wf;
                }
        }
    }
    #pragma unroll
    for (int mt = 0; mt < 4; ++mt)
        #pragma unroll
        for (int r = 0; r < 4; ++r) {
            float v = part[mt][r];
            v += __shfl_xor(v, 1); v += __shfl_xor(v, 2);
            v += __shfl_xor(v, 4); v += __shfl_xor(v, 8);
            part[mt][r] = v;
        }
    if (lm == 0) {
        #pragma unroll
        for (int mt = 0; mt < 4; ++mt)
            #pragma unroll
            for (int r = 0; r < 4; ++r)
                redS[w][mt * 16 + q * 4 + r] = part[mt][r];
    }
    __syncthreads();
    if (t < 64) {
        int row = row0 + t;
        if (row < M)
            score_c[row] = redS[0][t] + redS[1][t] + redS[2][t] + redS[3][t] + b_full[0];
    }
}

// ---------------- K4: softmax + ctx + emb -> ctx_bf[2048][96] ----------------
__global__ __launch_bounds__(64) void softmax_ctx_kernel(const float* __restrict__ score_c,
                                                         const int* __restrict__ rowidx,
                                                         const int* __restrict__ cntA,
                                                         const int* __restrict__ baseA,
                                                         const float* __restrict__ s_part,
                                                         const ushort* __restrict__ enc,
                                                         const float* __restrict__ end_pos,
                                                         const float* __restrict__ rel_pos,
                                                         const float* __restrict__ W_embed,
                                                         const float* __restrict__ b_embed,
                                                         const float* __restrict__ b_full,
                                                         ushort* __restrict__ ctx_bf) {
    int b = blockIdx.x, t = threadIdx.x;
    int cnt = cntA[b], base = baseA[b];
    // s_empty = sum of 32 dec partials + b_full
    float sp = (t < 32) ? s_part[(size_t)t * 2048 + b] : 0.f;
    #pragma unroll
    for (int o = 32; o > 0; o >>= 1) sp += __shfl_xor(sp, o);
    float se = sp + b_full[0];
    float sc = se;
    int ri = 0;
    if (t < cnt) { sc = score_c[base + t]; ri = rowidx[base + t]; }
    float mx = sc;
    #pragma unroll
    for (int o = 32; o > 0; o >>= 1) mx = fmaxf(mx, __shfl_xor(mx, o));
    float e = expf(sc - mx);
    float ssum = e;
    #pragma unroll
    for (int o = 32; o > 0; o >>= 1) ssum += __shfl_xor(ssum, o);
    __shared__ float aS[G];
    __shared__ int rS[G];
    aS[t] = e / ssum;
    rS[t] = ri;
    __syncthreads();
    float ctx = 0.f;
    for (int i = 0; i < cnt; ++i)
        ctx += aS[i] * bf2f(enc[(size_t)rS[i] * H_DIM + t]);
    ctx_bf[(size_t)b * 96 + t] = f2bf(ctx);
    if (t < EMB) {
        float e0 = end_pos[2*b], e1 = end_pos[2*b+1], e2 = rel_pos[2*b], e3 = rel_pos[2*b+1];
        float v = b_embed[t] + e0 * W_embed[0*EMB + t] + e1 * W_embed[1*EMB + t]
                             + e2 * W_embed[2*EMB + t] + e3 * W_embed[3*EMB + t];
        ctx_bf[(size_t)b * 96 + 64 + t] = f2bf(v > 0.f ? v : 0.f);
    }
    if (t < 28) ctx_bf[(size_t)b * 96 + 68 + t] = 0;
}

// ---------------- K5: out_bf = bf16(relu(ctx_bf @ Wot^T + b_out))  (MFMA, K=96) ----------------
__global__ __launch_bounds__(256) void out_mfma_kernel(const ushort* __restrict__ A,   // ctx_bf [2048][96]
                                                       const ushort* __restrict__ Bt,  // Wot [1024][96]
                                                       const float* __restrict__ bias,
                                                       ushort* __restrict__ out) {
    int t = threadIdx.x;
    int w = t >> 6, lane = t & 63;
    int lm = lane & 15, q = lane >> 4;
    int m0 = blockIdx.x * 64, n1 = blockIdx.y * 128;
    __shared__ __align__(16) ushort Asm[64][104];
    __shared__ __align__(16) ushort Bsm[128][104];

    {
        int r = t >> 2, pp = t & 3;
        #pragma unroll
        for (int ii = 0; ii < 3; ++ii) {
            int c8 = (pp * 3 + ii) * 8;
            *(uint4*)&Asm[r][c8] = *(const uint4*)&A[(size_t)(m0 + r) * 96 + c8];
        }
    }
    {
        int r = t >> 1, pp = t & 1;
        #pragma unroll
        for (int ii = 0; ii < 6; ++ii) {
            int c8 = (pp * 6 + ii) * 8;
            *(uint4*)&Bsm[r][c8] = *(const uint4*)&Bt[(size_t)(n1 + r) * 96 + c8];
        }
    }
    __syncthreads();

    floatx4 acc[4][2];
    #pragma unroll
    for (int mt = 0; mt < 4; ++mt)
        #pragma unroll
        for (int nt = 0; nt < 2; ++nt) acc[mt][nt] = (floatx4){0.f, 0.f, 0.f, 0.f};

    #pragma unroll
    for (int ks = 0; ks < 96; ks += 32) {
        short8 af[4], bfr[2];
        #pragma unroll
        for (int mt = 0; mt < 4; ++mt)
            af[mt] = *(const short8*)&Asm[mt * 16 + lm][ks + q * 8];
        #pragma unroll
        for (int nt = 0; nt < 2; ++nt)
            bfr[nt] = *(const short8*)&Bsm[w * 32 + nt * 16 + lm][ks + q * 8];
        #pragma unroll
        for (int mt = 0; mt < 4; ++mt)
            #pragma unroll
            for (int nt = 0; nt < 2; ++nt)
                acc[mt][nt] = __builtin_amdgcn_mfma_f32_16x16x32_bf16(af[mt], bfr[nt], acc[mt][nt], 0, 0, 0);
    }
    #pragma unroll
    for (int nt = 0; nt < 2; ++nt) {
        int col = n1 + w * 32 + nt * 16 + lm;
        float bv = bias[col];
        #pragma unroll
        for (int mt = 0; mt < 4; ++mt)
            #pragma unroll
            for (int r = 0; r < 4; ++r) {
                int row = m0 + mt * 16 + q * 4 + r;
                out[(size_t)row * ATT + col] = f2bf(fmaxf(acc[mt][nt][r] + bv, 0.f));
            }
    }
}

// ---------------- K6: x = out_bf @ Wt^T + b_mlp (MFMA, 64x64 tiles, 512 blocks) + BN stats ----------------
__global__ __launch_bounds__(256) void mlp_mfma_kernel(const ushort* __restrict__ A,   // [2048][1024] bf16
                                                       const ushort* __restrict__ Bt,  // [1024][1024] bf16
                                                       const float* __restrict__ bias,
                                                       float* __restrict__ X,
                                                       float* __restrict__ sums) {
    int t = threadIdx.x;
    int w = t >> 6, lane = t & 63;
    int lm = lane & 15, q = lane >> 4;
    int m0 = blockIdx.x * 64, n0 = blockIdx.y * 64;
    __shared__ __align__(16) ushort Asm[64][72];
    __shared__ __align__(16) ushort Bsm[64][72];

    floatx4 acc[4];
    #pragma unroll
    for (int mt = 0; mt < 4; ++mt) acc[mt] = (floatx4){0.f, 0.f, 0.f, 0.f};

    for (int k0 = 0; k0 < 1024; k0 += 64) {
        __syncthreads();
        #pragma unroll
        for (int i = 0; i < 4; ++i) {
            int flat = t + 256 * i;
            int r = flat >> 4, c4 = (flat & 15) * 4;
            *(uint2*)&Asm[r][c4] = *(const uint2*)&A[(size_t)(m0 + r) * 1024 + k0 + c4];
            *(uint2*)&Bsm[r][c4] = *(const uint2*)&Bt[(size_t)(n0 + r) * 1024 + k0 + c4];
        }
        __syncthreads();
        #pragma unroll
        for (int ks = 0; ks < 64; ks += 32) {
            short8 af[4], bfr;
            #pragma unroll
            for (int mt = 0; mt < 4; ++mt)
                af[mt] = *(const short8*)&Asm[mt * 16 + lm][ks + q * 8];
            bfr = *(const short8*)&Bsm[w * 16 + lm][ks + q * 8];
            #pragma unroll
            for (int mt = 0; mt < 4; ++mt)
                acc[mt] = __builtin_amdgcn_mfma_f32_16x16x32_bf16(af[mt], bfr, acc[mt], 0, 0, 0);
        }
    }
    int col = n0 + w * 16 + lm;
    float bv = bias[col];
    float s1 = 0.f, s2 = 0.f;
    #pragma unroll
    for (int mt = 0; mt < 4; ++mt)
        #pragma unroll
        for (int r = 0; r < 4; ++r) {
            int row = m0 + mt * 16 + q * 4 + r;
            float v = acc[mt][r] + bv;
            X[(size_t)row * 1024 + col] = v;
            s1 += v; s2 += v * v;
        }
    s1 += __shfl_xor(s1, 16); s1 += __shfl_xor(s1, 32);
    s2 += __shfl_xor(s2, 16); s2 += __shfl_xor(s2, 32);
    if (q == 0) {
        atomicAdd(&sums[col], s1);
        atomicAdd(&sums[ATT + col], s2);
    }
}

// ---------------- K7: normalize + relu -> d_out (float4) ----------------
__global__ __launch_bounds__(256) void bn_kernel(const float* __restrict__ X,
                                                 const float* __restrict__ sums,
                                                 const float* __restrict__ gamma,
                                                 const float* __restrict__ beta,
                                                 float* __restrict__ out) {
    size_t i4 = ((size_t)blockIdx.x * 256 + threadIdx.x) * 4;
    int f = (int)(i4 & 1023);
    float4 xv = *(const float4*)&X[i4];
    float4 s1 = *(const float4*)&sums[f];
    float4 s2 = *(const float4*)&sums[ATT + f];
    float4 gm = *(const float4*)&gamma[f];
    float4 bt = *(const float4*)&beta[f];
    float4 ov;
    float mu, var, v;
    mu = s1.x * (1.f / BB); var = s2.x * (1.f / BB) - mu * mu;
    v = (xv.x - mu) * rsqrtf(var + 1e-5f) * gm.x + bt.x; ov.x = v > 0.f ? v : 0.f;
    mu = s1.y * (1.f / BB); var = s2.y * (1.f / BB) - mu * mu;
    v = (xv.y - mu) * rsqrtf(var + 1e-5f) * gm.y + bt.y; ov.y = v > 0.f ? v : 0.f;
    mu = s1.z * (1.f / BB); var = s2.z * (1.f / BB) - mu * mu;
    v = (xv.z - mu) * rsqrtf(var + 1e-5f) * gm.z + bt.z; ov.z = v > 0.f ? v : 0.f;
    mu = s1.w * (1.f / BB); var = s2.w * (1.f / BB) - mu * mu;
    v = (xv.w - mu) * rsqrtf(var + 1e-5f) * gm.w + bt.w; ov.w = v > 0.f ? v : 0.f;
    *(float4*)&out[i4] = ov;
}

extern "C" void kernel_launch(void* const* d_in, const int* in_sizes, int n_in,
                              void* d_out, int out_size, void* d_ws, size_t ws_size,
                              hipStream_t stream) {
    const float* h        = (const float*)d_in[0];
    const float* end_pos  = (const float*)d_in[2];
    const float* rel_pos  = (const float*)d_in[3];
    const float* W_enc    = (const float*)d_in[4];
    const float* b_enc    = (const float*)d_in[5];
    const float* W_dec    = (const float*)d_in[6];
    const float* b_dec    = (const float*)d_in[7];
    const float* w_full   = (const float*)d_in[8];
    const float* b_full   = (const float*)d_in[9];
    const float* W_embed  = (const float*)d_in[10];
    const float* b_embed  = (const float*)d_in[11];
    const float* W_out    = (const float*)d_in[12];
    const float* b_out    = (const float*)d_in[13];
    const float* W_mlp    = (const float*)d_in[14];
    const float* b_mlp    = (const float*)d_in[15];
    const float* bn_gamma = (const float*)d_in[16];
    const float* bn_beta  = (const float*)d_in[17];

    float* ws = (float*)d_ws;
    ushort* enc     = (ushort*)ws;                 // 131072 x 64 bf16
    ushort* h_bf    = (ushort*)(ws + 4194304);     // 2048 x 64 bf16
    ushort* Wte     = (ushort*)(ws + 4259840);     // 1024 x 64 bf16
    ushort* Wdt     = (ushort*)(ws + 4292608);     // 1024 x 64 bf16
    ushort* Wot     = (ushort*)(ws + 4325376);     // 1024 x 96 bf16
    ushort* Wt      = (ushort*)(ws + 4374528);     // 1024 x 1024 bf16
    ushort* ctx_bf  = (ushort*)(ws + 4898816);     // 2048 x 96 bf16
    ushort* out_bf  = (ushort*)(ws + 4997120);     // 2048 x 1024 bf16
    float*  x       = ws + 6045696;                // 2048 x 1024 fp32
    float*  dec_r   = ws + 8388608;                // 2048 x 1024 fp32
    int*    rowidx  = (int*)(ws + 10485760);       // 131,072
    float*  score_c = ws + 10616832;               // 131,072
    int*    cntA    = (int*)(ws + 10747904);       // 2,048
    int*    baseA   = (int*)(ws + 10749952);       // 2,048
    int*    counter = (int*)(ws + 10752000);       // 64
    float*  sums    = ws + 10752064;               // 2,048
    float*  s_part  = ws + 10754112;               // 32 x 2048
    int*    flag    = (int*)(ws + 10819648);       // 64

    prep_kernel<<<PREP_BLOCKS, 256, 0, stream>>>(h, end_pos, W_enc, W_dec, W_out, W_mlp,
                                                 enc, h_bf, Wte, Wdt, Wot, Wt,
                                                 rowidx, cntA, baseA, counter, sums, flag);
    dec_mfma_kernel<<<dim3(32, 8), 256, 0, stream>>>(h_bf, Wdt, b_dec, b_enc, w_full, dec_r, s_part);
    scoresC_mfma_kernel<<<MAXROWS / 64, 256, 0, stream>>>(enc, rowidx, counter, dec_r, Wte,
                                                          w_full, b_full, score_c);
    softmax_ctx_kernel<<<BB, 64, 0, stream>>>(score_c, rowidx, cntA, baseA, s_part, enc,
                                              end_pos, rel_pos, W_embed, b_embed, b_full, ctx_bf);
    out_mfma_kernel<<<dim3(32, 8), 256, 0, stream>>>(ctx_bf, Wot, b_out, out_bf);
    mlp_mfma_kernel<<<dim3(32, 16), 256, 0, stream>>>(out_bf, Wt, b_mlp, x, sums);
    bn_kernel<<<2048, 256, 0, stream>>>(x, sums, bn_gamma, bn_beta, (float*)d_out);
}